// Round 9
// baseline (369.437 us; speedup 1.0000x reference)
//
#include <hip/hip_runtime.h>
#include <hip/hip_bf16.h>

#define N_EMBD 1024
#define N_HEAD 16
#define HEADSZ 64
#define BATCH  2
#define SEQ    2048
#define ROWS   (BATCH*SEQ)   /* 4096 */

typedef __attribute__((ext_vector_type(8))) short bf16x8;
typedef __attribute__((ext_vector_type(4))) float f32x4;

__device__ __forceinline__ short f2bs(float v){
    union { __hip_bfloat16 b; short s; } u; u.b = __float2bfloat16(v); return u.s;
}
__device__ __forceinline__ short scale8th(short s){   // exact: *0.125 (pow2)
    union { unsigned i; float f; } u; u.i = ((unsigned)(unsigned short)s) << 16;
    return f2bs(u.f * 0.125f);
}
__device__ __forceinline__ void gload16(const short* g, short* l){
    __builtin_amdgcn_global_load_lds(
        (const __attribute__((address_space(1))) unsigned int*)g,
        (__attribute__((address_space(3))) unsigned int*)l, 16, 0, 0);
}

// ---------------------------------------------------------------------------
// Transpose + f32->bf16 convert: out[j][i] = in[i][j]; in is [R][Cc] f32.
// ---------------------------------------------------------------------------
__global__ __launch_bounds__(256) void tr_cvt(const float* __restrict__ in,
                                              short* __restrict__ out,
                                              int R, int Cc,
                                              size_t in_z, size_t out_z)
{
    __shared__ float t[32][33];
    const int tx = threadIdx.x & 31, ty = threadIdx.x >> 5;
    const int j0 = blockIdx.x * 32, i0 = blockIdx.y * 32;
    const float* ip = in + (size_t)blockIdx.z * in_z;
    short* op = out + (size_t)blockIdx.z * out_z;
#pragma unroll
    for (int p = 0; p < 4; ++p)
        t[ty + p * 8][tx] = ip[(size_t)(i0 + ty + p * 8) * Cc + j0 + tx];
    __syncthreads();
#pragma unroll
    for (int p = 0; p < 4; ++p)
        op[(size_t)(j0 + ty + p * 8) * R + i0 + tx] = f2bs(t[tx][ty + p * 8]);
}

// Fused Wq/Wk/Wv transpose: z = which*16 + head; per-head [1024][64] -> [64][1024]
__global__ __launch_bounds__(256) void tr3_cvt(const float* __restrict__ Wq,
                                               const float* __restrict__ Wk,
                                               const float* __restrict__ Wv,
                                               short* __restrict__ w2t)
{
    __shared__ float t[32][33];
    const int tx = threadIdx.x & 31, ty = threadIdx.x >> 5;
    const int which = blockIdx.z >> 4, head = blockIdx.z & 15;
    const int j0 = blockIdx.x * 32, i0 = blockIdx.y * 32;
    const float* ip = (which == 0 ? Wq : which == 1 ? Wk : Wv) + (size_t)head * 65536;
    short* op = w2t + (size_t)which * 1048576 + (size_t)head * 65536;
#pragma unroll
    for (int p = 0; p < 4; ++p)
        t[ty + p * 8][tx] = ip[(size_t)(i0 + ty + p * 8) * 64 + j0 + tx];
    __syncthreads();
#pragma unroll
    for (int p = 0; p < 4; ++p)
        op[(size_t)(j0 + ty + p * 8) * 1024 + i0 + tx] = f2bs(t[tx][ty + p * 8]);
}

// ---------------------------------------------------------------------------
// bf16 transpose of the V slice of qkv: vt[c][token] = qkv[token][2048+c]
// ---------------------------------------------------------------------------
__global__ __launch_bounds__(256) void vt_tr(const short* __restrict__ qkv,
                                             short* __restrict__ vt)
{
    __shared__ short t[64][65];
    const int tid = threadIdx.x;
    const int sr = tid >> 2, sc = (tid & 3) * 16;
    const int col0 = blockIdx.x * 64, tok0 = blockIdx.y * 64;
    const short* ip = qkv + (size_t)(tok0 + sr) * 3072 + 2048 + col0 + sc;
    bf16x8 v0 = *(const bf16x8*)ip;
    bf16x8 v1 = *(const bf16x8*)(ip + 8);
#pragma unroll
    for (int i = 0; i < 8; ++i) { t[sr][sc + i] = v0[i]; t[sr][sc + 8 + i] = v1[i]; }
    __syncthreads();
    bf16x8 a, bq;
#pragma unroll
    for (int i = 0; i < 8; ++i) { a[i] = t[sc + i][sr]; bq[i] = t[sc + 8 + i][sr]; }
    short* op = vt + (size_t)(col0 + sr) * 4096 + tok0 + sc;
    *(bf16x8*)op = a;
    *(bf16x8*)(op + 8) = bq;
}

// ---------------------------------------------------------------------------
// LayerNorm (LN1): one block per row of 1024, float4 loads, bf16 output
// ---------------------------------------------------------------------------
__global__ __launch_bounds__(256) void ln_k(const float* __restrict__ x,
                                            const float* __restrict__ g,
                                            const float* __restrict__ bta,
                                            short* __restrict__ out)
{
    const int row = blockIdx.x;
    const int tid = threadIdx.x;
    const float* xr = x + (size_t)row * N_EMBD;
    float4 v = *(const float4*)(xr + tid * 4);
    float s  = v.x + v.y + v.z + v.w;
    float s2 = v.x * v.x + v.y * v.y + v.z * v.z + v.w * v.w;
#pragma unroll
    for (int off = 32; off; off >>= 1) {
        s  += __shfl_xor(s,  off, 64);
        s2 += __shfl_xor(s2, off, 64);
    }
    __shared__ float rs[4], rs2[4];
    const int wave = tid >> 6, lane = tid & 63;
    if (lane == 0) { rs[wave] = s; rs2[wave] = s2; }
    __syncthreads();
    s  = rs[0] + rs[1] + rs[2] + rs[3];
    s2 = rs2[0] + rs2[1] + rs2[2] + rs2[3];
    const float mean = s * (1.f / N_EMBD);
    const float var  = s2 * (1.f / N_EMBD) - mean * mean;
    const float rsig = rsqrtf(var + 1e-5f);
    float4 gv = *(const float4*)(g + tid * 4);
    float4 bv = *(const float4*)(bta + tid * 4);
    short4 o;
    o.x = f2bs((v.x - mean) * rsig * gv.x + bv.x);
    o.y = f2bs((v.y - mean) * rsig * gv.y + bv.y);
    o.z = f2bs((v.z - mean) * rsig * gv.z + bv.z);
    o.w = f2bs((v.w - mean) * rsig * gv.w + bv.w);
    *(short4*)(out + (size_t)row * N_EMBD + tid * 4) = o;
}

// ---------------------------------------------------------------------------
// Fused proj-finalize + LN2: x2 = p0+p1+bias+x (write f32); h2 = LN(x2) bf16.
// ---------------------------------------------------------------------------
__global__ __launch_bounds__(256) void pln_fin(const float* __restrict__ p0,
                                               const float* __restrict__ p1,
                                               const float* __restrict__ bias,
                                               const float* __restrict__ x,
                                               const float* __restrict__ g,
                                               const float* __restrict__ bta,
                                               float* __restrict__ x2,
                                               short* __restrict__ h2)
{
    const int row = blockIdx.x, tid = threadIdx.x;
    const size_t base = (size_t)row * N_EMBD + tid * 4;
    float4 a  = *(const float4*)(p0 + base);
    float4 c  = *(const float4*)(p1 + base);
    float4 xx = *(const float4*)(x + base);
    float4 bb = *(const float4*)(bias + tid * 4);
    float4 v;
    v.x = a.x + c.x + xx.x + bb.x;
    v.y = a.y + c.y + xx.y + bb.y;
    v.z = a.z + c.z + xx.z + bb.z;
    v.w = a.w + c.w + xx.w + bb.w;
    *(float4*)(x2 + base) = v;
    float s  = v.x + v.y + v.z + v.w;
    float s2 = v.x * v.x + v.y * v.y + v.z * v.z + v.w * v.w;
#pragma unroll
    for (int off = 32; off; off >>= 1) {
        s  += __shfl_xor(s,  off, 64);
        s2 += __shfl_xor(s2, off, 64);
    }
    __shared__ float rs[4], rs2[4];
    const int wave = tid >> 6, lane = tid & 63;
    if (lane == 0) { rs[wave] = s; rs2[wave] = s2; }
    __syncthreads();
    s  = rs[0] + rs[1] + rs[2] + rs[3];
    s2 = rs2[0] + rs2[1] + rs2[2] + rs2[3];
    const float mean = s * (1.f / N_EMBD);
    const float var  = s2 * (1.f / N_EMBD) - mean * mean;
    const float rsig = rsqrtf(var + 1e-5f);
    float4 gv = *(const float4*)(g + tid * 4);
    float4 bv = *(const float4*)(bta + tid * 4);
    short4 o;
    o.x = f2bs((v.x - mean) * rsig * gv.x + bv.x);
    o.y = f2bs((v.y - mean) * rsig * gv.y + bv.y);
    o.z = f2bs((v.z - mean) * rsig * gv.z + bv.z);
    o.w = f2bs((v.w - mean) * rsig * gv.w + bv.w);
    *(short4*)(h2 + base) = o;
}

// ---------------------------------------------------------------------------
// MFMA GEMM 128x128, 3-buffer depth-2 counted-vmcnt pipeline (R15).
// Used for QKV only (N=3072 underfills a 256-tile grid).
// ---------------------------------------------------------------------------
__global__ __launch_bounds__(256) void mfma_gemm(
    const short* __restrict__ A,    // [M][K] bf16
    const short* __restrict__ Bt,   // [N][K] bf16
    const float* __restrict__ bias,
    const float* __restrict__ resid,
    float* __restrict__ outf,
    float* __restrict__ outf2,
    short* __restrict__ outb,
    int M, int N, int K, int kz, int relu)
{
    __shared__ __align__(16) short As[3][128 * 32];
    __shared__ __align__(16) short Bs[3][128 * 32];
    const int tid  = threadIdx.x;
    const int lane = tid & 63, w = tid >> 6;
    const int quad = lane >> 4, l16 = lane & 15;
    const int row0 = blockIdx.y * 128, col0 = blockIdx.x * 128;
    const int wm = (w >> 1) * 64, wn = (w & 1) * 64;
    const int koff = blockIdx.z * kz;
    const int kend = kz ? kz : K;
    const int nk   = kend >> 5;          // 32-wide K tiles

    f32x4 acc[4][4];
#pragma unroll
    for (int i = 0; i < 4; ++i)
#pragma unroll
        for (int j = 0; j < 4; ++j)
            acc[i][j] = f32x4{0.f, 0.f, 0.f, 0.f};

    const int c0  = w * 128 + lane;
    const int c1  = c0 + 64;
    const int ar0 = c0 >> 2, ak0 = (((c0 & 3) ^ ((ar0 >> 1) & 3))) * 8; // swizzled
    const int ar1 = c1 >> 2, ak1 = (((c1 & 3) ^ ((ar1 >> 1) & 3))) * 8;
    const short* aG0 = A  + (size_t)(row0 + ar0) * K + koff + ak0;
    const short* aG1 = A  + (size_t)(row0 + ar1) * K + koff + ak1;
    const short* bG0 = Bt + (size_t)(col0 + ar0) * K + koff + ak0;
    const short* bG1 = Bt + (size_t)(col0 + ar1) * K + koff + ak1;
    const int lofs = w * 1024;

    const int gsw = (quad ^ ((l16 >> 1) & 3)) * 8;   // swizzled frag chunk

    // prologue: stage T0 -> buf0, T1 -> buf1 (4 loads/wave each)
    gload16(aG0, As[0] + lofs);
    gload16(aG1, As[0] + lofs + 512);
    gload16(bG0, Bs[0] + lofs);
    gload16(bG1, Bs[0] + lofs + 512);
    if (nk > 1) {
        gload16(aG0 + 32, As[1] + lofs);
        gload16(aG1 + 32, As[1] + lofs + 512);
        gload16(bG0 + 32, Bs[1] + lofs);
        gload16(bG1 + 32, Bs[1] + lofs + 512);
    }

    for (int k = 0; k < nk; ++k) {
        if (k + 1 < nk) asm volatile("s_waitcnt vmcnt(4)" ::: "memory");
        else            asm volatile("s_waitcnt vmcnt(0)" ::: "memory");
        __builtin_amdgcn_s_barrier();
        if (k + 2 < nk) {
            const int nb = (k + 2) % 3;
            const int ko = (k + 2) * 32;
            gload16(aG0 + ko, As[nb] + lofs);
            gload16(aG1 + ko, As[nb] + lofs + 512);
            gload16(bG0 + ko, Bs[nb] + lofs);
            gload16(bG1 + ko, Bs[nb] + lofs + 512);
        }
        const int cur = k % 3;

        bf16x8 af[4], bfr[4];
#pragma unroll
        for (int i = 0; i < 4; ++i)
            af[i]  = *(const bf16x8*)(As[cur] + (wm + i * 16 + l16) * 32 + gsw);
#pragma unroll
        for (int j = 0; j < 4; ++j)
            bfr[j] = *(const bf16x8*)(Bs[cur] + (wn + j * 16 + l16) * 32 + gsw);
#pragma unroll
        for (int i = 0; i < 4; ++i)
#pragma unroll
            for (int j = 0; j < 4; ++j)
                acc[i][j] = __builtin_amdgcn_mfma_f32_16x16x32_bf16(
                    af[i], bfr[j], acc[i][j], 0, 0, 0);
    }

    float* of = blockIdx.z ? outf2 : outf;
#pragma unroll
    for (int i = 0; i < 4; ++i) {
        const int rbase = row0 + wm + i * 16 + quad * 4;
#pragma unroll
        for (int j = 0; j < 4; ++j) {
            const int c = col0 + wn + j * 16 + l16;
            const float bv = bias ? bias[c] : 0.f;
#pragma unroll
            for (int r = 0; r < 4; ++r) {
                float v = acc[i][j][r] + bv;
                if (relu) v = fmaxf(v, 0.f);
                const size_t idx = (size_t)(rbase + r) * N + c;
                if (resid) v += resid[idx];
                if (outb) outb[idx] = f2bs(v);
                else      of[idx] = v;
            }
        }
    }
}

// ---------------------------------------------------------------------------
// MFMA GEMM 256x256, 8 waves (2M x 4N), per-wave 128x64 output (R16).
// Depth-1 double-buffer with R14 issue-order. FF1: 256 blocks = 1/CU.
// ---------------------------------------------------------------------------
__global__ __launch_bounds__(512, 2) void mfma_gemm256(
    const short* __restrict__ A,    // [M][K] bf16
    const short* __restrict__ Bt,   // [N][K] bf16
    const float* __restrict__ bias,
    short* __restrict__ outb,       // [M][N] bf16
    int N, int K, int relu)
{
    __shared__ __align__(16) short As[2][256 * 32];
    __shared__ __align__(16) short Bs[2][256 * 32];
    const int tid  = threadIdx.x;              // 0..511
    const int lane = tid & 63, w = tid >> 6;   // 8 waves
    const int quad = lane >> 4, l16 = lane & 15;
    const int row0 = blockIdx.y * 256, col0 = blockIdx.x * 256;
    const int wm = (w >> 2) * 128;             // 2 row-halves
    const int wn = (w & 3) * 64;               // 4 col-quarters
    const int nk = K >> 5;

    f32x4 acc[8][4];
#pragma unroll
    for (int i = 0; i < 8; ++i)
#pragma unroll
        for (int j = 0; j < 4; ++j)
            acc[i][j] = f32x4{0.f, 0.f, 0.f, 0.f};

    const int i0 = tid, i1 = tid + 512;
    const int ar0 = i0 >> 2, ak0 = ((i0 & 3) ^ ((ar0 >> 1) & 3)) * 8;
    const int ar1 = i1 >> 2, ak1 = ((i1 & 3) ^ ((ar1 >> 1) & 3)) * 8;
    const short* aG0 = A  + (size_t)(row0 + ar0) * K + ak0;
    const short* aG1 = A  + (size_t)(row0 + ar1) * K + ak1;
    const short* bG0 = Bt + (size_t)(col0 + ar0) * K + ak0;
    const short* bG1 = Bt + (size_t)(col0 + ar1) * K + ak1;
    const int lofs = w * 512;                  // wave-uniform LDS base (shorts)

    const int gsw = (quad ^ ((l16 >> 1) & 3)) * 8;

    // prologue: stage T0 -> buf 0
    gload16(aG0, As[0] + lofs);
    gload16(aG1, As[0] + 4096 + lofs);
    gload16(bG0, Bs[0] + lofs);
    gload16(bG1, Bs[0] + 4096 + lofs);
    asm volatile("s_waitcnt vmcnt(0)" ::: "memory");
    __builtin_amdgcn_s_barrier();

    for (int k = 0; k < nk; ++k) {
        const int cur = k & 1;
        if (k + 1 < nk) {                      // stage next tile -> other buf
            const int ko = (k + 1) * 32;
            const int nb = cur ^ 1;
            gload16(aG0 + ko, As[nb] + lofs);
            gload16(aG1 + ko, As[nb] + 4096 + lofs);
            gload16(bG0 + ko, Bs[nb] + lofs);
            gload16(bG1 + ko, Bs[nb] + 4096 + lofs);
        }

        bf16x8 af[8], bfr[4];
#pragma unroll
        for (int i = 0; i < 8; ++i)
            af[i]  = *(const bf16x8*)(As[cur] + (wm + i * 16 + l16) * 32 + gsw);
#pragma unroll
        for (int j = 0; j < 4; ++j)
            bfr[j] = *(const bf16x8*)(Bs[cur] + (wn + j * 16 + l16) * 32 + gsw);
#pragma unroll
        for (int i = 0; i < 8; ++i)
#pragma unroll
            for (int j = 0; j < 4; ++j)
                acc[i][j] = __builtin_amdgcn_mfma_f32_16x16x32_bf16(
                    af[i], bfr[j], acc[i][j], 0, 0, 0);

        asm volatile("s_waitcnt vmcnt(0)" ::: "memory");
        __builtin_amdgcn_s_barrier();
    }

#pragma unroll
    for (int i = 0; i < 8; ++i) {
        const int rbase = row0 + wm + i * 16 + quad * 4;
#pragma unroll
        for (int j = 0; j < 4; ++j) {
            const int c = col0 + wn + j * 16 + l16;
            const float bv = bias[c];
#pragma unroll
            for (int r = 0; r < 4; ++r) {
                float v = acc[i][j][r] + bv;
                if (relu) v = fmaxf(v, 0.f);
                outb[(size_t)(rbase + r) * N + c] = f2bs(v);
            }
        }
    }
}

// ---------------------------------------------------------------------------
// MFMA GEMM 256x128 (R18), 8 waves (4M x 2N), per-wave 64x64 output, for
// the N=1024 split-K GEMMs (proj, FF2). Replaces gemm64 whose 32x64 wave
// tile was LDS-read-BW-bound (R17 counters: 194cy/block-step = 24KB @
// 128B/cy LDS peak, MfmaUtil 23%). reads/MFMA: 0.75 -> 0.5; at 0.5 the
// MFMA pipe (~614cy/step) binds before LDS (~500cy). 3-buffer depth-2
// counted-vmcnt(3) pipeline; 72KB LDS; grid (8,16,2)=256 blocks = 1/CU.
// XCD row-band swizzle: XCD k owns row-tiles {2k,2k+1} x all 8 col-tiles.
// Raw f32 partials (z -> outf/outf2), output N fixed 1024.
// ---------------------------------------------------------------------------
__global__ __launch_bounds__(512, 2) void mfma_gemm256x128(
    const short* __restrict__ A,    // [4096][K] bf16
    const short* __restrict__ Bt,   // [1024][K] bf16
    float* __restrict__ outf,
    float* __restrict__ outf2,
    int K, int kz)
{
    __shared__ __align__(16) short As[3][256 * 32];
    __shared__ __align__(16) short Bs[3][128 * 32];
    const int tid  = threadIdx.x;              // 0..511
    const int lane = tid & 63, w = tid >> 6;   // 8 waves
    const int quad = lane >> 4, l16 = lane & 15;
    // XCD row-band swizzle over 128 tiles per z-half
    const int lin  = (int)blockIdx.y * 8 + (int)blockIdx.x;   // 0..127
    const int swz  = (lin & 7) * 16 + (lin >> 3);             // bijective
    const int row0 = (swz >> 3) * 256;          // row-tile 0..15
    const int col0 = (swz & 7) * 128;           // col-tile 0..7
    const int wr = w >> 1, wc = w & 1;          // 4M x 2N wave tiles (64x64)
    const int koff = blockIdx.z * kz;
    const int nk   = kz >> 5;

    f32x4 acc[4][4];
#pragma unroll
    for (int i = 0; i < 4; ++i)
#pragma unroll
        for (int j = 0; j < 4; ++j)
            acc[i][j] = f32x4{0.f, 0.f, 0.f, 0.f};

    // A staging: 1024 chunks/buffer, thread t does chunks t and t+512
    const int ar0 = tid >> 2, ak0 = ((tid & 3) ^ ((ar0 >> 1) & 3)) * 8;
    const short* aG0 = A + (size_t)(row0 + ar0) * K + koff + ak0;
    const short* aG1 = A + (size_t)(row0 + ar0 + 128) * K + koff + ak0;
    // B staging: 512 chunks/buffer, thread t does chunk t
    const short* bG0 = Bt + (size_t)(col0 + ar0) * K + koff + ak0;
    const int lofs = w * 512;                   // wave-uniform LDS base

    const int gsw = (quad ^ ((l16 >> 1) & 3)) * 8;

    // prologue: stage T0 -> buf0, T1 -> buf1 (3 loads/thread each)
    gload16(aG0, As[0] + lofs);
    gload16(aG1, As[0] + 4096 + lofs);
    gload16(bG0, Bs[0] + lofs);
    if (nk > 1) {
        gload16(aG0 + 32, As[1] + lofs);
        gload16(aG1 + 32, As[1] + 4096 + lofs);
        gload16(bG0 + 32, Bs[1] + lofs);
    }

    for (int k = 0; k < nk; ++k) {
        if (k + 1 < nk) asm volatile("s_waitcnt vmcnt(3)" ::: "memory");
        else            asm volatile("s_waitcnt vmcnt(0)" ::: "memory");
        __builtin_amdgcn_s_barrier();
        if (k + 2 < nk) {
            const int nb = (k + 2) % 3;
            const int ko = (k + 2) * 32;
            gload16(aG0 + ko, As[nb] + lofs);
            gload16(aG1 + ko, As[nb] + 4096 + lofs);
            gload16(bG0 + ko, Bs[nb] + lofs);
        }
        const int cur = k % 3;

        bf16x8 af[4], bfr[4];
#pragma unroll
        for (int i = 0; i < 4; ++i)
            af[i]  = *(const bf16x8*)(As[cur] + (wr * 64 + i * 16 + l16) * 32 + gsw);
#pragma unroll
        for (int j = 0; j < 4; ++j)
            bfr[j] = *(const bf16x8*)(Bs[cur] + (wc * 64 + j * 16 + l16) * 32 + gsw);
#pragma unroll
        for (int i = 0; i < 4; ++i)
#pragma unroll
            for (int j = 0; j < 4; ++j)
                acc[i][j] = __builtin_amdgcn_mfma_f32_16x16x32_bf16(
                    af[i], bfr[j], acc[i][j], 0, 0, 0);
    }

    float* of = blockIdx.z ? outf2 : outf;
#pragma unroll
    for (int i = 0; i < 4; ++i) {
        const int rbase = row0 + wr * 64 + i * 16 + quad * 4;
#pragma unroll
        for (int j = 0; j < 4; ++j) {
            const int c = col0 + wc * 64 + j * 16 + l16;
#pragma unroll
            for (int r = 0; r < 4; ++r)
                of[(size_t)(rbase + r) * 1024 + c] = acc[i][j][r];
        }
    }
}

// ---------------------------------------------------------------------------
// FF2 finalize: out = p0 + out + bias + x2   (all f32, N=1024 bias period)
// ---------------------------------------------------------------------------
__global__ __launch_bounds__(256) void ff2_fin(const float* __restrict__ p0,
                                               const float* __restrict__ bias,
                                               const float* __restrict__ x2,
                                               float* __restrict__ out)
{
    const size_t i = ((size_t)blockIdx.x * 256 + threadIdx.x) * 4;
    float4 a = *(const float4*)(p0 + i);
    float4 b = *(const float4*)(out + i);
    float4 r = *(const float4*)(x2 + i);
    float4 bb = *(const float4*)(bias + (i & 1023));
    float4 o;
    o.x = a.x + b.x + r.x + bb.x;
    o.y = a.y + b.y + r.y + bb.y;
    o.z = a.z + b.z + r.z + bb.z;
    o.w = a.w + b.w + r.w + bb.w;
    *(float4*)(out + i) = o;
}

// ---------------------------------------------------------------------------
// MFMA flash attention (R17): TWO-PASS pairing + XCD-pinned heads.
// grid = (bh=32, pair=16): XCD = bh%8 (K/V L2-resident); each block does
// qt = pair and qt = 31-pair -> uniform 33 tiles. Swapped QK^T softmax.
// ---------------------------------------------------------------------------
__global__ __launch_bounds__(256) void attn_k(const short* __restrict__ qkv,
                                              const short* __restrict__ vt,
                                              short* __restrict__ att)
{
    __shared__ __align__(16) short Ks[2][64 * 64];   // [s][d] swizzled
    __shared__ __align__(16) short Vs[2][64 * 64];   // [d][s] swizzled
    __shared__ __align__(16) short Ps[64 * 64];      // [q][s] XOR-swizzled
    const int tid  = threadIdx.x;
    const int lane = tid & 63, w = tid >> 6;         // w in 0..3
    const int quad = lane >> 4, l16 = lane & 15;
    const int bh = blockIdx.x, b = bh >> 4, head = bh & 15;  // XCD=bh%8

    const int srow = lane >> 3;                       // 0..7
    const int sw   = ((lane & 7) ^ srow) * 8;         // staging swizzle (shorts)
    const int cidx = (quad ^ (l16 & 7)) * 8;          // frag-read swizzle

#pragma unroll
    for (int pass = 0; pass < 2; ++pass) {
        const int qt = pass == 0 ? (int)blockIdx.y : 31 - (int)blockIdx.y;
        const int t0 = qt * 64;
        const int ntiles = qt + 1;

        // Q fragments (registers), scale folded in (exact pow2)
        const short* qp = qkv + (size_t)(b * SEQ + t0 + w * 16 + l16) * 3072
                          + head * 64 + quad * 8;
        bf16x8 qf0 = *(const bf16x8*)qp;
        bf16x8 qf1 = *(const bf16x8*)(qp + 32);
#pragma unroll
        for (int i = 0; i < 8; ++i) { qf0[i] = scale8th(qf0[i]); qf1[i] = scale8th(qf1[i]); }

        // per-lane softmax state for q-row (t0 + w*16 + l16)
        float mrow = -INFINITY, lrow = 0.f;
        f32x4 O[4];                                   // D[q=w*16+quad*4+r][d=jn*16+l16]
#pragma unroll
        for (int jn = 0; jn < 4; ++jn) O[jn] = f32x4{0.f, 0.f, 0.f, 0.f};

        // guard: previous pass fully done before overwriting buf0
        asm volatile("s_waitcnt vmcnt(0) lgkmcnt(0)\n\ts_barrier" ::: "memory");
        {   // prefetch tile 0 -> buffer 0 (wave w: K rows / V d-rows [w*16,+16))
            const short* kg = qkv + (size_t)(b * SEQ + w * 16 + srow) * 3072
                              + 1024 + head * 64 + sw;
            const short* vg = vt + (size_t)(head * 64 + w * 16 + srow) * 4096
                              + b * SEQ + sw;
            short* kL = Ks[0] + w * 1024;
            short* vL = Vs[0] + w * 1024;
            gload16(kg, kL); gload16(kg + (size_t)8 * 3072, kL + 512);
            gload16(vg, vL); gload16(vg + (size_t)8 * 4096, vL + 512);
        }

        for (int kt = 0; kt < ntiles; ++kt) {
            const int cur = kt & 1;
            // prefetched tile kt landed (all waves), prev compute done
            asm volatile("s_waitcnt vmcnt(0) lgkmcnt(0)\n\ts_barrier" ::: "memory");
            if (kt + 1 < ntiles) {
                const int s1 = (kt + 1) * 64;
                const short* kg = qkv + (size_t)(b * SEQ + s1 + w * 16 + srow) * 3072
                                  + 1024 + head * 64 + sw;
                const short* vg = vt + (size_t)(head * 64 + w * 16 + srow) * 4096
                                  + b * SEQ + s1 + sw;
                short* kL = Ks[cur ^ 1] + w * 1024;
                short* vL = Vs[cur ^ 1] + w * 1024;
                gload16(kg, kL); gload16(kg + (size_t)8 * 3072, kL + 512);
                gload16(vg, vL); gload16(vg + (size_t)8 * 4096, vL + 512);
            }

            // --- S^T = K.Q^T : D[key=jn*16+quad*4+r][q=l16] (swapped) ---
            f32x4 S[4];
            const short* Kb = Ks[cur];
#pragma unroll
            for (int jn = 0; jn < 4; ++jn) {
                S[jn] = f32x4{0.f, 0.f, 0.f, 0.f};
                const short* kp = Kb + (jn * 16 + l16) * 64;
                bf16x8 b0 = *(const bf16x8*)(kp + cidx);
                bf16x8 b1 = *(const bf16x8*)(kp + (cidx ^ 32));
                S[jn] = __builtin_amdgcn_mfma_f32_16x16x32_bf16(b0, qf0, S[jn], 0, 0, 0);
                S[jn] = __builtin_amdgcn_mfma_f32_16x16x32_bf16(b1, qf1, S[jn], 0, 0, 0);
            }

            // --- softmax: q = t0 + w*16 + l16 fixed per lane ---
            float Sv[4][4];
            const int qrow = t0 + w * 16 + l16;
            const int s0 = kt * 64;
#pragma unroll
            for (int jn = 0; jn < 4; ++jn)
#pragma unroll
                for (int r = 0; r < 4; ++r)
                    Sv[jn][r] = S[jn][r];
            if (kt == ntiles - 1) {   // diagonal tile
#pragma unroll
                for (int jn = 0; jn < 4; ++jn)
#pragma unroll
                    for (int r = 0; r < 4; ++r)
                        if (s0 + jn * 16 + quad * 4 + r > qrow) Sv[jn][r] = -INFINITY;
            }
            float tmx[4];
#pragma unroll
            for (int jn = 0; jn < 4; ++jn)
                tmx[jn] = fmaxf(fmaxf(Sv[jn][0], Sv[jn][1]), fmaxf(Sv[jn][2], Sv[jn][3]));
            float pm = fmaxf(fmaxf(tmx[0], tmx[1]), fmaxf(tmx[2], tmx[3]));
            pm = fmaxf(pm, __shfl_xor(pm, 16, 64));
            pm = fmaxf(pm, __shfl_xor(pm, 32, 64));  // full 64-key max
            const float mn    = fmaxf(mrow, pm);
            const float alpha = __expf(mrow - mn);   // 0 on first tile
#pragma unroll
            for (int jn = 0; jn < 4; ++jn)
#pragma unroll
                for (int r = 0; r < 4; ++r)
                    Sv[jn][r] = __expf(Sv[jn][r] - mn);
            float tsm[4];
#pragma unroll
            for (int jn = 0; jn < 4; ++jn)
                tsm[jn] = (Sv[jn][0] + Sv[jn][1]) + (Sv[jn][2] + Sv[jn][3]);
            float ps = (tsm[0] + tsm[1]) + (tsm[2] + tsm[3]);
            ps += __shfl_xor(ps, 16, 64);
            ps += __shfl_xor(ps, 32, 64);
            lrow = lrow * alpha + ps;
            mrow = mn;
            // rescale O: alpha for O-row (quad*4+r) lives at lane l16==quad*4+r
#pragma unroll
            for (int r = 0; r < 4; ++r) {
                const float a = __shfl(alpha, quad * 4 + r, 64);
#pragma unroll
                for (int jn = 0; jn < 4; ++jn) O[jn][r] *= a;
            }

            // --- P^T -> LDS rows [q][key] ---
#pragma unroll
            for (int jn = 0; jn < 4; ++jn) {
                short4 pv;
                pv.x = f2bs(Sv[jn][0]); pv.y = f2bs(Sv[jn][1]);
                pv.z = f2bs(Sv[jn][2]); pv.w = f2bs(Sv[jn][3]);
                const int prow = w * 16 + l16;
                const int pcol = jn * 16 + quad * 4;  // 4-aligned
                const int chunk = (pcol >> 3) ^ (l16 & 7);
                *(short4*)(Ps + prow * 64 + chunk * 8 + (pcol & 7)) = pv;
            }
            asm volatile("s_waitcnt lgkmcnt(0)" ::: "memory");

            // --- O += P.V ---
            const short* pp = Ps + (w * 16 + l16) * 64;
            bf16x8 pf0 = *(const bf16x8*)(pp + cidx);
            bf16x8 pf1 = *(const bf16x8*)(pp + (cidx ^ 32));
            const short* Vb = Vs[cur];
#pragma unroll
            for (int jn = 0; jn < 4; ++jn) {
                const short* vp = Vb + (jn * 16 + l16) * 64;
                bf16x8 v0 = *(const bf16x8*)(vp + cidx);
                bf16x8 v1 = *(const bf16x8*)(vp + (cidx ^ 32));
                O[jn] = __builtin_amdgcn_mfma_f32_16x16x32_bf16(pf0, v0, O[jn], 0, 0, 0);
                O[jn] = __builtin_amdgcn_mfma_f32_16x16x32_bf16(pf1, v1, O[jn], 0, 0, 0);
            }
        }

        // --- write O (rows quad*4+r need 1/l from lane l16==quad*4+r) ---
#pragma unroll
        for (int r = 0; r < 4; ++r) {
            const float lr  = __shfl(lrow, quad * 4 + r, 64);
            const float inv = 1.f / lr;
            const size_t rowoff = (size_t)(b * SEQ + t0 + w * 16 + quad * 4 + r) * N_EMBD
                                  + head * 64 + l16;
#pragma unroll
            for (int jn = 0; jn < 4; ++jn)
                att[rowoff + jn * 16] = f2bs(O[jn][r] * inv);
        }
    }
}

// ---------------------------------------------------------------------------
extern "C" void kernel_launch(void* const* d_in, const int* in_sizes, int n_in,
                              void* d_out, int out_size, void* d_ws, size_t ws_size,
                              hipStream_t stream)
{
    const float* x     = (const float*)d_in[0];
    const float* Wq    = (const float*)d_in[1];
    const float* Wk    = (const float*)d_in[2];
    const float* Wv    = (const float*)d_in[3];
    const float* Wproj = (const float*)d_in[4];
    const float* bproj = (const float*)d_in[5];
    const float* g1    = (const float*)d_in[6];
    const float* b1    = (const float*)d_in[7];
    const float* g2    = (const float*)d_in[8];
    const float* b2    = (const float*)d_in[9];
    const float* Wff1  = (const float*)d_in[10];
    const float* bff1  = (const float*)d_in[11];
    const float* Wff2  = (const float*)d_in[12];
    const float* bff2  = (const float*)d_in[13];
    float* out = (float*)d_out;

    char* ws = (char*)d_ws;
    short* w2t  = (short*)(ws + 0);          // [3072][1024] bf16 (dead after QKV)
    short* wpt  = (short*)(ws + 6291456);    // [1024][1024] (dead after proj)
    short* wf1t = (short*)(ws + 8388608);    // [4096][1024] (dead after FF1)
    short* wf2t = (short*)(ws + 16777216);   // [1024][4096]
    short* h    = (short*)(ws + 25165824);   // [4096][1024] (=h2)
    short* qkv  = (short*)(ws + 33554432);   // [4096][3072] (dead after attn)
    short* vt   = (short*)(ws + 58720256);   // [1024][4096] (dead after attn)
    short* att  = (short*)(ws + 67108864);   // [4096][1024]
    float* x2   = (float*)(ws + 75497472);   // [4096][1024] f32
    short* h2   = h;
    float* p0p  = (float*)(ws + 33554432);   // proj partials over dead qkv/vt
    float* p1p  = (float*)(ws + 50331648);
    short* ff   = qkv;                       // [4096][4096] (p0p/p1p dead by FF1)
    float* p0f  = (float*)(ws + 0);          // FF2 partial over w2t+wpt+wf1t (dead)

    tr3_cvt<<<dim3(2, 32, 48),  256, 0, stream>>>(Wq, Wk, Wv, w2t);
    tr_cvt<<<dim3(32, 32, 1),  256, 0, stream>>>(Wproj, wpt,  1024, 1024, 0, 0);
    tr_cvt<<<dim3(128, 32, 1), 256, 0, stream>>>(Wff1, wf1t,  1024, 4096, 0, 0);
    tr_cvt<<<dim3(32, 128, 1), 256, 0, stream>>>(Wff2, wf2t,  4096, 1024, 0, 0);

    ln_k<<<ROWS, 256, 0, stream>>>(x, g1, b1, h);
    // QKV: [4096,1024] x [1024,3072] -> bf16 qkv
    mfma_gemm<<<dim3(3072 / 128, ROWS / 128), 256, 0, stream>>>(
        h, w2t, nullptr, nullptr, nullptr, nullptr, qkv, ROWS, 3072, N_EMBD, 0, 0);
    vt_tr<<<dim3(16, 64), 256, 0, stream>>>(qkv, vt);
    // attn: grid (bh=32, pair=16) -> XCD = bh%8; uniform 33 tiles/block
    attn_k<<<dim3(BATCH * N_HEAD, 16), 256, 0, stream>>>(qkv, vt, att);
    // proj split-K=2, 256x128 tiles (256 blocks) -> raw partials p0p/p1p
    mfma_gemm256x128<<<dim3(8, 16, 2), 512, 0, stream>>>(att, wpt, p0p, p1p,
                                                         N_EMBD, 512);
    // fused proj-epilogue + LN2: x2 = p0p+p1p+bproj+x ; h2 = LN(x2)
    pln_fin<<<ROWS, 256, 0, stream>>>(p0p, p1p, bproj, x, g2, b2, x2, h2);
    // FF1 + bias + relu -> bf16 ff   (256^2 tile, 8-wave, 256 blocks = 1/CU)
    mfma_gemm256<<<dim3(4096 / 256, ROWS / 256), 512, 0, stream>>>(
        h2, wf1t, bff1, ff, 4096, N_EMBD, 1);
    // FF2 split-K=2, 256x128 tiles (256 blocks) -> p0f / out (raw)
    mfma_gemm256x128<<<dim3(8, 16, 2), 512, 0, stream>>>(ff, wf2t, p0f, out,
                                                         4096, 2048);
    // out = p0f + out + bias + x2
    ff2_fin<<<ROWS * N_EMBD / 1024, 256, 0, stream>>>(p0f, bff2, x2, out);
}

// Round 10
// 358.590 us; speedup vs baseline: 1.0302x; 1.0302x over previous
//
#include <hip/hip_runtime.h>
#include <hip/hip_bf16.h>

#define N_EMBD 1024
#define N_HEAD 16
#define HEADSZ 64
#define BATCH  2
#define SEQ    2048
#define ROWS   (BATCH*SEQ)   /* 4096 */

typedef __attribute__((ext_vector_type(8))) short bf16x8;
typedef __attribute__((ext_vector_type(4))) float f32x4;

__device__ __forceinline__ short f2bs(float v){
    union { __hip_bfloat16 b; short s; } u; u.b = __float2bfloat16(v); return u.s;
}
__device__ __forceinline__ short scale8th(short s){   // exact: *0.125 (pow2)
    union { unsigned i; float f; } u; u.i = ((unsigned)(unsigned short)s) << 16;
    return f2bs(u.f * 0.125f);
}
__device__ __forceinline__ void gload16(const short* g, short* l){
    __builtin_amdgcn_global_load_lds(
        (const __attribute__((address_space(1))) unsigned int*)g,
        (__attribute__((address_space(3))) unsigned int*)l, 16, 0, 0);
}

// ---------------------------------------------------------------------------
// Transpose + f32->bf16 convert: out[j][i] = in[i][j]; in is [R][Cc] f32.
// ---------------------------------------------------------------------------
__global__ __launch_bounds__(256) void tr_cvt(const float* __restrict__ in,
                                              short* __restrict__ out,
                                              int R, int Cc,
                                              size_t in_z, size_t out_z)
{
    __shared__ float t[32][33];
    const int tx = threadIdx.x & 31, ty = threadIdx.x >> 5;
    const int j0 = blockIdx.x * 32, i0 = blockIdx.y * 32;
    const float* ip = in + (size_t)blockIdx.z * in_z;
    short* op = out + (size_t)blockIdx.z * out_z;
#pragma unroll
    for (int p = 0; p < 4; ++p)
        t[ty + p * 8][tx] = ip[(size_t)(i0 + ty + p * 8) * Cc + j0 + tx];
    __syncthreads();
#pragma unroll
    for (int p = 0; p < 4; ++p)
        op[(size_t)(j0 + ty + p * 8) * R + i0 + tx] = f2bs(t[tx][ty + p * 8]);
}

// Fused Wq/Wk/Wv transpose: z = which*16 + head; per-head [1024][64] -> [64][1024]
__global__ __launch_bounds__(256) void tr3_cvt(const float* __restrict__ Wq,
                                               const float* __restrict__ Wk,
                                               const float* __restrict__ Wv,
                                               short* __restrict__ w2t)
{
    __shared__ float t[32][33];
    const int tx = threadIdx.x & 31, ty = threadIdx.x >> 5;
    const int which = blockIdx.z >> 4, head = blockIdx.z & 15;
    const int j0 = blockIdx.x * 32, i0 = blockIdx.y * 32;
    const float* ip = (which == 0 ? Wq : which == 1 ? Wk : Wv) + (size_t)head * 65536;
    short* op = w2t + (size_t)which * 1048576 + (size_t)head * 65536;
#pragma unroll
    for (int p = 0; p < 4; ++p)
        t[ty + p * 8][tx] = ip[(size_t)(i0 + ty + p * 8) * 64 + j0 + tx];
    __syncthreads();
#pragma unroll
    for (int p = 0; p < 4; ++p)
        op[(size_t)(j0 + ty + p * 8) * 1024 + i0 + tx] = f2bs(t[tx][ty + p * 8]);
}

// ---------------------------------------------------------------------------
// LayerNorm (LN1): one block per row of 1024, float4 loads, bf16 output
// ---------------------------------------------------------------------------
__global__ __launch_bounds__(256) void ln_k(const float* __restrict__ x,
                                            const float* __restrict__ g,
                                            const float* __restrict__ bta,
                                            short* __restrict__ out)
{
    const int row = blockIdx.x;
    const int tid = threadIdx.x;
    const float* xr = x + (size_t)row * N_EMBD;
    float4 v = *(const float4*)(xr + tid * 4);
    float s  = v.x + v.y + v.z + v.w;
    float s2 = v.x * v.x + v.y * v.y + v.z * v.z + v.w * v.w;
#pragma unroll
    for (int off = 32; off; off >>= 1) {
        s  += __shfl_xor(s,  off, 64);
        s2 += __shfl_xor(s2, off, 64);
    }
    __shared__ float rs[4], rs2[4];
    const int wave = tid >> 6, lane = tid & 63;
    if (lane == 0) { rs[wave] = s; rs2[wave] = s2; }
    __syncthreads();
    s  = rs[0] + rs[1] + rs[2] + rs[3];
    s2 = rs2[0] + rs2[1] + rs2[2] + rs2[3];
    const float mean = s * (1.f / N_EMBD);
    const float var  = s2 * (1.f / N_EMBD) - mean * mean;
    const float rsig = rsqrtf(var + 1e-5f);
    float4 gv = *(const float4*)(g + tid * 4);
    float4 bv = *(const float4*)(bta + tid * 4);
    short4 o;
    o.x = f2bs((v.x - mean) * rsig * gv.x + bv.x);
    o.y = f2bs((v.y - mean) * rsig * gv.y + bv.y);
    o.z = f2bs((v.z - mean) * rsig * gv.z + bv.z);
    o.w = f2bs((v.w - mean) * rsig * gv.w + bv.w);
    *(short4*)(out + (size_t)row * N_EMBD + tid * 4) = o;
}

// ---------------------------------------------------------------------------
// Fused proj-finalize + LN2: x2 = p0+p1+bias+x (write f32); h2 = LN(x2) bf16.
// ---------------------------------------------------------------------------
__global__ __launch_bounds__(256) void pln_fin(const float* __restrict__ p0,
                                               const float* __restrict__ p1,
                                               const float* __restrict__ bias,
                                               const float* __restrict__ x,
                                               const float* __restrict__ g,
                                               const float* __restrict__ bta,
                                               float* __restrict__ x2,
                                               short* __restrict__ h2)
{
    const int row = blockIdx.x, tid = threadIdx.x;
    const size_t base = (size_t)row * N_EMBD + tid * 4;
    float4 a  = *(const float4*)(p0 + base);
    float4 c  = *(const float4*)(p1 + base);
    float4 xx = *(const float4*)(x + base);
    float4 bb = *(const float4*)(bias + tid * 4);
    float4 v;
    v.x = a.x + c.x + xx.x + bb.x;
    v.y = a.y + c.y + xx.y + bb.y;
    v.z = a.z + c.z + xx.z + bb.z;
    v.w = a.w + c.w + xx.w + bb.w;
    *(float4*)(x2 + base) = v;
    float s  = v.x + v.y + v.z + v.w;
    float s2 = v.x * v.x + v.y * v.y + v.z * v.z + v.w * v.w;
#pragma unroll
    for (int off = 32; off; off >>= 1) {
        s  += __shfl_xor(s,  off, 64);
        s2 += __shfl_xor(s2, off, 64);
    }
    __shared__ float rs[4], rs2[4];
    const int wave = tid >> 6, lane = tid & 63;
    if (lane == 0) { rs[wave] = s; rs2[wave] = s2; }
    __syncthreads();
    s  = rs[0] + rs[1] + rs[2] + rs[3];
    s2 = rs2[0] + rs2[1] + rs2[2] + rs2[3];
    const float mean = s * (1.f / N_EMBD);
    const float var  = s2 * (1.f / N_EMBD) - mean * mean;
    const float rsig = rsqrtf(var + 1e-5f);
    float4 gv = *(const float4*)(g + tid * 4);
    float4 bv = *(const float4*)(bta + tid * 4);
    short4 o;
    o.x = f2bs((v.x - mean) * rsig * gv.x + bv.x);
    o.y = f2bs((v.y - mean) * rsig * gv.y + bv.y);
    o.z = f2bs((v.z - mean) * rsig * gv.z + bv.z);
    o.w = f2bs((v.w - mean) * rsig * gv.w + bv.w);
    *(short4*)(h2 + base) = o;
}

// ---------------------------------------------------------------------------
// MFMA GEMM 128x128, 3-buffer depth-2 counted-vmcnt pipeline (R15).
// Used for QKV. R19: V-region blocks (col0>=2048, block-uniform) write
// TRANSPOSED bf16 directly into vtout[c-2048][token] as short4 over the 4
// consecutive-token acc lanes -> vt_tr kernel deleted (saves 32MB traffic).
// ---------------------------------------------------------------------------
__global__ __launch_bounds__(256) void mfma_gemm(
    const short* __restrict__ A,    // [M][K] bf16
    const short* __restrict__ Bt,   // [N][K] bf16
    const float* __restrict__ bias,
    const float* __restrict__ resid,
    float* __restrict__ outf,
    float* __restrict__ outf2,
    short* __restrict__ outb,
    short* __restrict__ vtout,      // if set: cols>=2048 -> vt[c-2048][tok]
    int M, int N, int K, int kz, int relu)
{
    __shared__ __align__(16) short As[3][128 * 32];
    __shared__ __align__(16) short Bs[3][128 * 32];
    const int tid  = threadIdx.x;
    const int lane = tid & 63, w = tid >> 6;
    const int quad = lane >> 4, l16 = lane & 15;
    const int row0 = blockIdx.y * 128, col0 = blockIdx.x * 128;
    const int wm = (w >> 1) * 64, wn = (w & 1) * 64;
    const int koff = blockIdx.z * kz;
    const int kend = kz ? kz : K;
    const int nk   = kend >> 5;          // 32-wide K tiles

    f32x4 acc[4][4];
#pragma unroll
    for (int i = 0; i < 4; ++i)
#pragma unroll
        for (int j = 0; j < 4; ++j)
            acc[i][j] = f32x4{0.f, 0.f, 0.f, 0.f};

    const int c0  = w * 128 + lane;
    const int c1  = c0 + 64;
    const int ar0 = c0 >> 2, ak0 = (((c0 & 3) ^ ((ar0 >> 1) & 3))) * 8; // swizzled
    const int ar1 = c1 >> 2, ak1 = (((c1 & 3) ^ ((ar1 >> 1) & 3))) * 8;
    const short* aG0 = A  + (size_t)(row0 + ar0) * K + koff + ak0;
    const short* aG1 = A  + (size_t)(row0 + ar1) * K + koff + ak1;
    const short* bG0 = Bt + (size_t)(col0 + ar0) * K + koff + ak0;
    const short* bG1 = Bt + (size_t)(col0 + ar1) * K + koff + ak1;
    const int lofs = w * 1024;

    const int gsw = (quad ^ ((l16 >> 1) & 3)) * 8;   // swizzled frag chunk

    // prologue: stage T0 -> buf0, T1 -> buf1 (4 loads/wave each)
    gload16(aG0, As[0] + lofs);
    gload16(aG1, As[0] + lofs + 512);
    gload16(bG0, Bs[0] + lofs);
    gload16(bG1, Bs[0] + lofs + 512);
    if (nk > 1) {
        gload16(aG0 + 32, As[1] + lofs);
        gload16(aG1 + 32, As[1] + lofs + 512);
        gload16(bG0 + 32, Bs[1] + lofs);
        gload16(bG1 + 32, Bs[1] + lofs + 512);
    }

    for (int k = 0; k < nk; ++k) {
        if (k + 1 < nk) asm volatile("s_waitcnt vmcnt(4)" ::: "memory");
        else            asm volatile("s_waitcnt vmcnt(0)" ::: "memory");
        __builtin_amdgcn_s_barrier();
        if (k + 2 < nk) {
            const int nb = (k + 2) % 3;
            const int ko = (k + 2) * 32;
            gload16(aG0 + ko, As[nb] + lofs);
            gload16(aG1 + ko, As[nb] + lofs + 512);
            gload16(bG0 + ko, Bs[nb] + lofs);
            gload16(bG1 + ko, Bs[nb] + lofs + 512);
        }
        const int cur = k % 3;

        bf16x8 af[4], bfr[4];
#pragma unroll
        for (int i = 0; i < 4; ++i)
            af[i]  = *(const bf16x8*)(As[cur] + (wm + i * 16 + l16) * 32 + gsw);
#pragma unroll
        for (int j = 0; j < 4; ++j)
            bfr[j] = *(const bf16x8*)(Bs[cur] + (wn + j * 16 + l16) * 32 + gsw);
#pragma unroll
        for (int i = 0; i < 4; ++i)
#pragma unroll
            for (int j = 0; j < 4; ++j)
                acc[i][j] = __builtin_amdgcn_mfma_f32_16x16x32_bf16(
                    af[i], bfr[j], acc[i][j], 0, 0, 0);
    }

    if (vtout && col0 >= 2048) {     // V region: write transposed bf16
#pragma unroll
        for (int i = 0; i < 4; ++i) {
            const int rbase = row0 + wm + i * 16 + quad * 4;   // token base (x4)
#pragma unroll
            for (int j = 0; j < 4; ++j) {
                const int c = col0 + wn + j * 16 + l16 - 2048; // V channel
                short4 pv;
                pv.x = f2bs(acc[i][j][0]); pv.y = f2bs(acc[i][j][1]);
                pv.z = f2bs(acc[i][j][2]); pv.w = f2bs(acc[i][j][3]);
                *(short4*)(vtout + (size_t)c * 4096 + rbase) = pv;
            }
        }
        return;
    }

    float* of = blockIdx.z ? outf2 : outf;
#pragma unroll
    for (int i = 0; i < 4; ++i) {
        const int rbase = row0 + wm + i * 16 + quad * 4;
#pragma unroll
        for (int j = 0; j < 4; ++j) {
            const int c = col0 + wn + j * 16 + l16;
            const float bv = bias ? bias[c] : 0.f;
#pragma unroll
            for (int r = 0; r < 4; ++r) {
                float v = acc[i][j][r] + bv;
                if (relu) v = fmaxf(v, 0.f);
                const size_t idx = (size_t)(rbase + r) * N + c;
                if (resid) v += resid[idx];
                if (outb) outb[idx] = f2bs(v);
                else      of[idx] = v;
            }
        }
    }
}

// ---------------------------------------------------------------------------
// MFMA GEMM 256x256, 8 waves (2M x 4N), per-wave 128x64 output (R16).
// Depth-1 double-buffer with R14 issue-order. FF1: 256 blocks = 1/CU.
// ---------------------------------------------------------------------------
__global__ __launch_bounds__(512, 2) void mfma_gemm256(
    const short* __restrict__ A,    // [M][K] bf16
    const short* __restrict__ Bt,   // [N][K] bf16
    const float* __restrict__ bias,
    short* __restrict__ outb,       // [M][N] bf16
    int N, int K, int relu)
{
    __shared__ __align__(16) short As[2][256 * 32];
    __shared__ __align__(16) short Bs[2][256 * 32];
    const int tid  = threadIdx.x;              // 0..511
    const int lane = tid & 63, w = tid >> 6;   // 8 waves
    const int quad = lane >> 4, l16 = lane & 15;
    const int row0 = blockIdx.y * 256, col0 = blockIdx.x * 256;
    const int wm = (w >> 2) * 128;             // 2 row-halves
    const int wn = (w & 3) * 64;               // 4 col-quarters
    const int nk = K >> 5;

    f32x4 acc[8][4];
#pragma unroll
    for (int i = 0; i < 8; ++i)
#pragma unroll
        for (int j = 0; j < 4; ++j)
            acc[i][j] = f32x4{0.f, 0.f, 0.f, 0.f};

    const int i0 = tid, i1 = tid + 512;
    const int ar0 = i0 >> 2, ak0 = ((i0 & 3) ^ ((ar0 >> 1) & 3)) * 8;
    const int ar1 = i1 >> 2, ak1 = ((i1 & 3) ^ ((ar1 >> 1) & 3)) * 8;
    const short* aG0 = A  + (size_t)(row0 + ar0) * K + ak0;
    const short* aG1 = A  + (size_t)(row0 + ar1) * K + ak1;
    const short* bG0 = Bt + (size_t)(col0 + ar0) * K + ak0;
    const short* bG1 = Bt + (size_t)(col0 + ar1) * K + ak1;
    const int lofs = w * 512;                  // wave-uniform LDS base (shorts)

    const int gsw = (quad ^ ((l16 >> 1) & 3)) * 8;

    // prologue: stage T0 -> buf 0
    gload16(aG0, As[0] + lofs);
    gload16(aG1, As[0] + 4096 + lofs);
    gload16(bG0, Bs[0] + lofs);
    gload16(bG1, Bs[0] + 4096 + lofs);
    asm volatile("s_waitcnt vmcnt(0)" ::: "memory");
    __builtin_amdgcn_s_barrier();

    for (int k = 0; k < nk; ++k) {
        const int cur = k & 1;
        if (k + 1 < nk) {                      // stage next tile -> other buf
            const int ko = (k + 1) * 32;
            const int nb = cur ^ 1;
            gload16(aG0 + ko, As[nb] + lofs);
            gload16(aG1 + ko, As[nb] + 4096 + lofs);
            gload16(bG0 + ko, Bs[nb] + lofs);
            gload16(bG1 + ko, Bs[nb] + 4096 + lofs);
        }

        bf16x8 af[8], bfr[4];
#pragma unroll
        for (int i = 0; i < 8; ++i)
            af[i]  = *(const bf16x8*)(As[cur] + (wm + i * 16 + l16) * 32 + gsw);
#pragma unroll
        for (int j = 0; j < 4; ++j)
            bfr[j] = *(const bf16x8*)(Bs[cur] + (wn + j * 16 + l16) * 32 + gsw);
#pragma unroll
        for (int i = 0; i < 8; ++i)
#pragma unroll
            for (int j = 0; j < 4; ++j)
                acc[i][j] = __builtin_amdgcn_mfma_f32_16x16x32_bf16(
                    af[i], bfr[j], acc[i][j], 0, 0, 0);

        asm volatile("s_waitcnt vmcnt(0)" ::: "memory");
        __builtin_amdgcn_s_barrier();
    }

#pragma unroll
    for (int i = 0; i < 8; ++i) {
        const int rbase = row0 + wm + i * 16 + quad * 4;
#pragma unroll
        for (int j = 0; j < 4; ++j) {
            const int c = col0 + wn + j * 16 + l16;
            const float bv = bias[c];
#pragma unroll
            for (int r = 0; r < 4; ++r) {
                float v = acc[i][j][r] + bv;
                if (relu) v = fmaxf(v, 0.f);
                outb[(size_t)(rbase + r) * N + c] = f2bs(v);
            }
        }
    }
}

// ---------------------------------------------------------------------------
// MFMA GEMM 64x128, 3-buffer depth-2 counted-vmcnt pipeline (3 loads/tile
// per wave -> vmcnt(3)). XCD-chunked bijective block swizzle. 36 KB LDS
// (4 blocks/CU). Raw f32 partials (z -> outf/outf2). For proj and FF2.
// (R19: restored from R17 after R18's 256x128@1-block/CU regressed —
// independent-block concurrency beats deeper intra-block pipelining here.)
// ---------------------------------------------------------------------------
__global__ __launch_bounds__(256) void mfma_gemm64(
    const short* __restrict__ A,    // [4096][K] bf16
    const short* __restrict__ Bt,   // [1024][K] bf16
    float* __restrict__ outf,
    float* __restrict__ outf2,
    int K, int kz)
{
    __shared__ __align__(16) short As[3][64 * 32];
    __shared__ __align__(16) short Bs[3][128 * 32];
    const int tid  = threadIdx.x;
    const int lane = tid & 63, w = tid >> 6;
    const int quad = lane >> 4, l16 = lane & 15;
    const int lin  = (int)blockIdx.y * 8 + (int)blockIdx.x;   // 0..511
    const int swz  = (lin & 7) * 64 + (lin >> 3);
    const int col0 = (swz & 7) * 128;
    const int row0 = (swz >> 3) * 64;
    const int wr = w >> 1, wc = w & 1;                        // 2x2 wave tiles
    const int koff = blockIdx.z * kz;
    const int nk   = kz >> 5;

    f32x4 acc[2][4];
#pragma unroll
    for (int i = 0; i < 2; ++i)
#pragma unroll
        for (int j = 0; j < 4; ++j)
            acc[i][j] = f32x4{0.f, 0.f, 0.f, 0.f};

    // A staging: 1 gload16/thread (64 rows x 32 K)
    const int ia  = w * 64 + lane;                 // 0..255
    const int ar  = ia >> 2;                       // 0..63
    const int aak = ((ia & 3) ^ ((ar >> 1) & 3)) * 8;
    const short* aG = A + (size_t)(row0 + ar) * K + koff + aak;
    const int aofs = w * 512;
    // B staging: 2 gload16/thread (128 rows x 32 K)
    const int c0  = w * 128 + lane;
    const int c1  = c0 + 64;
    const int br0 = c0 >> 2, bk0 = ((c0 & 3) ^ ((br0 >> 1) & 3)) * 8;
    const int br1 = c1 >> 2, bk1 = ((c1 & 3) ^ ((br1 >> 1) & 3)) * 8;
    const short* bG0 = Bt + (size_t)(col0 + br0) * K + koff + bk0;
    const short* bG1 = Bt + (size_t)(col0 + br1) * K + koff + bk1;
    const int bofs = w * 1024;

    const int gsw = (quad ^ ((l16 >> 1) & 3)) * 8;

    // prologue: stage T0 -> buf0, T1 -> buf1
    gload16(aG, As[0] + aofs);
    gload16(bG0, Bs[0] + bofs);
    gload16(bG1, Bs[0] + bofs + 512);
    if (nk > 1) {
        gload16(aG + 32, As[1] + aofs);
        gload16(bG0 + 32, Bs[1] + bofs);
        gload16(bG1 + 32, Bs[1] + bofs + 512);
    }

    for (int k = 0; k < nk; ++k) {
        if (k + 1 < nk) asm volatile("s_waitcnt vmcnt(3)" ::: "memory");
        else            asm volatile("s_waitcnt vmcnt(0)" ::: "memory");
        __builtin_amdgcn_s_barrier();
        if (k + 2 < nk) {
            const int nb = (k + 2) % 3;
            const int ko = (k + 2) * 32;
            gload16(aG + ko, As[nb] + aofs);
            gload16(bG0 + ko, Bs[nb] + bofs);
            gload16(bG1 + ko, Bs[nb] + bofs + 512);
        }
        const int cur = k % 3;

        bf16x8 af[2], bfr[4];
#pragma unroll
        for (int i = 0; i < 2; ++i)
            af[i]  = *(const bf16x8*)(As[cur] + (wr * 32 + i * 16 + l16) * 32 + gsw);
#pragma unroll
        for (int j = 0; j < 4; ++j)
            bfr[j] = *(const bf16x8*)(Bs[cur] + (wc * 64 + j * 16 + l16) * 32 + gsw);
#pragma unroll
        for (int i = 0; i < 2; ++i)
#pragma unroll
            for (int j = 0; j < 4; ++j)
                acc[i][j] = __builtin_amdgcn_mfma_f32_16x16x32_bf16(
                    af[i], bfr[j], acc[i][j], 0, 0, 0);
    }

    float* of = blockIdx.z ? outf2 : outf;
#pragma unroll
    for (int i = 0; i < 2; ++i) {
        const int rbase = row0 + wr * 32 + i * 16 + quad * 4;
#pragma unroll
        for (int j = 0; j < 4; ++j) {
            const int c = col0 + wc * 64 + j * 16 + l16;
#pragma unroll
            for (int r = 0; r < 4; ++r)
                of[(size_t)(rbase + r) * 1024 + c] = acc[i][j][r];
        }
    }
}

// ---------------------------------------------------------------------------
// FF2 finalize: out = p0 + out + bias + x2   (all f32, N=1024 bias period)
// ---------------------------------------------------------------------------
__global__ __launch_bounds__(256) void ff2_fin(const float* __restrict__ p0,
                                               const float* __restrict__ bias,
                                               const float* __restrict__ x2,
                                               float* __restrict__ out)
{
    const size_t i = ((size_t)blockIdx.x * 256 + threadIdx.x) * 4;
    float4 a = *(const float4*)(p0 + i);
    float4 b = *(const float4*)(out + i);
    float4 r = *(const float4*)(x2 + i);
    float4 bb = *(const float4*)(bias + (i & 1023));
    float4 o;
    o.x = a.x + b.x + r.x + bb.x;
    o.y = a.y + b.y + r.y + bb.y;
    o.z = a.z + b.z + r.z + bb.z;
    o.w = a.w + b.w + r.w + bb.w;
    *(float4*)(out + i) = o;
}

// ---------------------------------------------------------------------------
// MFMA flash attention (R17 structure + R19 defer-max):
// grid = (bh=32, pair=16): XCD = bh%8 (K/V L2-resident); each block does
// qt = pair and qt = 31-pair -> uniform 33 tiles. Swapped QK^T softmax.
// R19: T13 defer-max (THR=8): skip O-rescale + max-update when no row's
// tile-max exceeds running max by >8 (P bounded by e^8, bf16-safe).
// ---------------------------------------------------------------------------
__global__ __launch_bounds__(256) void attn_k(const short* __restrict__ qkv,
                                              const short* __restrict__ vt,
                                              short* __restrict__ att)
{
    __shared__ __align__(16) short Ks[2][64 * 64];   // [s][d] swizzled
    __shared__ __align__(16) short Vs[2][64 * 64];   // [d][s] swizzled
    __shared__ __align__(16) short Ps[64 * 64];      // [q][s] XOR-swizzled
    const int tid  = threadIdx.x;
    const int lane = tid & 63, w = tid >> 6;         // w in 0..3
    const int quad = lane >> 4, l16 = lane & 15;
    const int bh = blockIdx.x, b = bh >> 4, head = bh & 15;  // XCD=bh%8

    const int srow = lane >> 3;                       // 0..7
    const int sw   = ((lane & 7) ^ srow) * 8;         // staging swizzle (shorts)
    const int cidx = (quad ^ (l16 & 7)) * 8;          // frag-read swizzle

#pragma unroll
    for (int pass = 0; pass < 2; ++pass) {
        const int qt = pass == 0 ? (int)blockIdx.y : 31 - (int)blockIdx.y;
        const int t0 = qt * 64;
        const int ntiles = qt + 1;

        // Q fragments (registers), scale folded in (exact pow2)
        const short* qp = qkv + (size_t)(b * SEQ + t0 + w * 16 + l16) * 3072
                          + head * 64 + quad * 8;
        bf16x8 qf0 = *(const bf16x8*)qp;
        bf16x8 qf1 = *(const bf16x8*)(qp + 32);
#pragma unroll
        for (int i = 0; i < 8; ++i) { qf0[i] = scale8th(qf0[i]); qf1[i] = scale8th(qf1[i]); }

        // per-lane softmax state for q-row (t0 + w*16 + l16)
        float mrow = -INFINITY, lrow = 0.f;
        f32x4 O[4];                                   // D[q=w*16+quad*4+r][d=jn*16+l16]
#pragma unroll
        for (int jn = 0; jn < 4; ++jn) O[jn] = f32x4{0.f, 0.f, 0.f, 0.f};

        // guard: previous pass fully done before overwriting buf0
        asm volatile("s_waitcnt vmcnt(0) lgkmcnt(0)\n\ts_barrier" ::: "memory");
        {   // prefetch tile 0 -> buffer 0 (wave w: K rows / V d-rows [w*16,+16))
            const short* kg = qkv + (size_t)(b * SEQ + w * 16 + srow) * 3072
                              + 1024 + head * 64 + sw;
            const short* vg = vt + (size_t)(head * 64 + w * 16 + srow) * 4096
                              + b * SEQ + sw;
            short* kL = Ks[0] + w * 1024;
            short* vL = Vs[0] + w * 1024;
            gload16(kg, kL); gload16(kg + (size_t)8 * 3072, kL + 512);
            gload16(vg, vL); gload16(vg + (size_t)8 * 4096, vL + 512);
        }

        for (int kt = 0; kt < ntiles; ++kt) {
            const int cur = kt & 1;
            // prefetched tile kt landed (all waves), prev compute done
            asm volatile("s_waitcnt vmcnt(0) lgkmcnt(0)\n\ts_barrier" ::: "memory");
            if (kt + 1 < ntiles) {
                const int s1 = (kt + 1) * 64;
                const short* kg = qkv + (size_t)(b * SEQ + s1 + w * 16 + srow) * 3072
                                  + 1024 + head * 64 + sw;
                const short* vg = vt + (size_t)(head * 64 + w * 16 + srow) * 4096
                                  + b * SEQ + s1 + sw;
                short* kL = Ks[cur ^ 1] + w * 1024;
                short* vL = Vs[cur ^ 1] + w * 1024;
                gload16(kg, kL); gload16(kg + (size_t)8 * 3072, kL + 512);
                gload16(vg, vL); gload16(vg + (size_t)8 * 4096, vL + 512);
            }

            // --- S^T = K.Q^T : D[key=jn*16+quad*4+r][q=l16] (swapped) ---
            f32x4 S[4];
            const short* Kb = Ks[cur];
#pragma unroll
            for (int jn = 0; jn < 4; ++jn) {
                S[jn] = f32x4{0.f, 0.f, 0.f, 0.f};
                const short* kp = Kb + (jn * 16 + l16) * 64;
                bf16x8 b0 = *(const bf16x8*)(kp + cidx);
                bf16x8 b1 = *(const bf16x8*)(kp + (cidx ^ 32));
                S[jn] = __builtin_amdgcn_mfma_f32_16x16x32_bf16(b0, qf0, S[jn], 0, 0, 0);
                S[jn] = __builtin_amdgcn_mfma_f32_16x16x32_bf16(b1, qf1, S[jn], 0, 0, 0);
            }

            // --- softmax: q = t0 + w*16 + l16 fixed per lane ---
            float Sv[4][4];
            const int qrow = t0 + w * 16 + l16;
            const int s0 = kt * 64;
#pragma unroll
            for (int jn = 0; jn < 4; ++jn)
#pragma unroll
                for (int r = 0; r < 4; ++r)
                    Sv[jn][r] = S[jn][r];
            if (kt == ntiles - 1) {   // diagonal tile
#pragma unroll
                for (int jn = 0; jn < 4; ++jn)
#pragma unroll
                    for (int r = 0; r < 4; ++r)
                        if (s0 + jn * 16 + quad * 4 + r > qrow) Sv[jn][r] = -INFINITY;
            }
            float tmx[4];
#pragma unroll
            for (int jn = 0; jn < 4; ++jn)
                tmx[jn] = fmaxf(fmaxf(Sv[jn][0], Sv[jn][1]), fmaxf(Sv[jn][2], Sv[jn][3]));
            float pm = fmaxf(fmaxf(tmx[0], tmx[1]), fmaxf(tmx[2], tmx[3]));
            pm = fmaxf(pm, __shfl_xor(pm, 16, 64));
            pm = fmaxf(pm, __shfl_xor(pm, 32, 64));  // full 64-key max

            // defer-max (T13): skip rescale when max growth <= 8 for ALL rows
            const bool skip = __all(pm - mrow <= 8.f);   // first tile: false
            const float mn = skip ? mrow : fmaxf(mrow, pm);
#pragma unroll
            for (int jn = 0; jn < 4; ++jn)
#pragma unroll
                for (int r = 0; r < 4; ++r)
                    Sv[jn][r] = __expf(Sv[jn][r] - mn);
            float tsm[4];
#pragma unroll
            for (int jn = 0; jn < 4; ++jn)
                tsm[jn] = (Sv[jn][0] + Sv[jn][1]) + (Sv[jn][2] + Sv[jn][3]);
            float ps = (tsm[0] + tsm[1]) + (tsm[2] + tsm[3]);
            ps += __shfl_xor(ps, 16, 64);
            ps += __shfl_xor(ps, 32, 64);
            if (skip) {
                lrow += ps;
            } else {
                const float alpha = __expf(mrow - mn);   // 0 on first tile
                lrow = lrow * alpha + ps;
                mrow = mn;
                // rescale O: alpha for O-row (quad*4+r) at lane l16==quad*4+r
#pragma unroll
                for (int r = 0; r < 4; ++r) {
                    const float a = __shfl(alpha, quad * 4 + r, 64);
#pragma unroll
                    for (int jn = 0; jn < 4; ++jn) O[jn][r] *= a;
                }
            }

            // --- P^T -> LDS rows [q][key] ---
#pragma unroll
            for (int jn = 0; jn < 4; ++jn) {
                short4 pv;
                pv.x = f2bs(Sv[jn][0]); pv.y = f2bs(Sv[jn][1]);
                pv.z = f2bs(Sv[jn][2]); pv.w = f2bs(Sv[jn][3]);
                const int prow = w * 16 + l16;
                const int pcol = jn * 16 + quad * 4;  // 4-aligned
                const int chunk = (pcol >> 3) ^ (l16 & 7);
                *(short4*)(Ps + prow * 64 + chunk * 8 + (pcol & 7)) = pv;
            }
            asm volatile("s_waitcnt lgkmcnt(0)" ::: "memory");

            // --- O += P.V ---
            const short* pp = Ps + (w * 16 + l16) * 64;
            bf16x8 pf0 = *(const bf16x8*)(pp + cidx);
            bf16x8 pf1 = *(const bf16x8*)(pp + (cidx ^ 32));
            const short* Vb = Vs[cur];
#pragma unroll
            for (int jn = 0; jn < 4; ++jn) {
                const short* vp = Vb + (jn * 16 + l16) * 64;
                bf16x8 v0 = *(const bf16x8*)(vp + cidx);
                bf16x8 v1 = *(const bf16x8*)(vp + (cidx ^ 32));
                O[jn] = __builtin_amdgcn_mfma_f32_16x16x32_bf16(pf0, v0, O[jn], 0, 0, 0);
                O[jn] = __builtin_amdgcn_mfma_f32_16x16x32_bf16(pf1, v1, O[jn], 0, 0, 0);
            }
        }

        // --- write O (rows quad*4+r need 1/l from lane l16==quad*4+r) ---
#pragma unroll
        for (int r = 0; r < 4; ++r) {
            const float lr  = __shfl(lrow, quad * 4 + r, 64);
            const float inv = 1.f / lr;
            const size_t rowoff = (size_t)(b * SEQ + t0 + w * 16 + quad * 4 + r) * N_EMBD
                                  + head * 64 + l16;
#pragma unroll
            for (int jn = 0; jn < 4; ++jn)
                att[rowoff + jn * 16] = f2bs(O[jn][r] * inv);
        }
    }
}

// ---------------------------------------------------------------------------
extern "C" void kernel_launch(void* const* d_in, const int* in_sizes, int n_in,
                              void* d_out, int out_size, void* d_ws, size_t ws_size,
                              hipStream_t stream)
{
    const float* x     = (const float*)d_in[0];
    const float* Wq    = (const float*)d_in[1];
    const float* Wk    = (const float*)d_in[2];
    const float* Wv    = (const float*)d_in[3];
    const float* Wproj = (const float*)d_in[4];
    const float* bproj = (const float*)d_in[5];
    const float* g1    = (const float*)d_in[6];
    const float* b1    = (const float*)d_in[7];
    const float* g2    = (const float*)d_in[8];
    const float* b2    = (const float*)d_in[9];
    const float* Wff1  = (const float*)d_in[10];
    const float* bff1  = (const float*)d_in[11];
    const float* Wff2  = (const float*)d_in[12];
    const float* bff2  = (const float*)d_in[13];
    float* out = (float*)d_out;

    char* ws = (char*)d_ws;
    short* w2t  = (short*)(ws + 0);          // [3072][1024] bf16 (dead after QKV)
    short* wpt  = (short*)(ws + 6291456);    // [1024][1024] (dead after proj)
    short* wf1t = (short*)(ws + 8388608);    // [4096][1024] (dead after FF1)
    short* wf2t = (short*)(ws + 16777216);   // [1024][4096]
    short* h    = (short*)(ws + 25165824);   // [4096][1024] (=h2)
    short* qkv  = (short*)(ws + 33554432);   // [4096][3072] (dead after attn)
    short* vt   = (short*)(ws + 58720256);   // [1024][4096] (dead after attn)
    short* att  = (short*)(ws + 67108864);   // [4096][1024]
    float* x2   = (float*)(ws + 75497472);   // [4096][1024] f32
    short* h2   = h;
    float* p0p  = (float*)(ws + 33554432);   // proj partials over dead qkv/vt
    float* p1p  = (float*)(ws + 50331648);
    short* ff   = qkv;                       // [4096][4096] (p0p/p1p dead by FF1)
    float* p0f  = (float*)(ws + 0);          // FF2 partial over w2t+wpt+wf1t (dead)

    tr3_cvt<<<dim3(2, 32, 48),  256, 0, stream>>>(Wq, Wk, Wv, w2t);
    tr_cvt<<<dim3(32, 32, 1),  256, 0, stream>>>(Wproj, wpt,  1024, 1024, 0, 0);
    tr_cvt<<<dim3(128, 32, 1), 256, 0, stream>>>(Wff1, wf1t,  1024, 4096, 0, 0);
    tr_cvt<<<dim3(32, 128, 1), 256, 0, stream>>>(Wff2, wf2t,  4096, 1024, 0, 0);

    ln_k<<<ROWS, 256, 0, stream>>>(x, g1, b1, h);
    // QKV: [4096,1024] x [1024,3072] -> bf16 qkv; V cols written transposed
    // into vt directly (vt_tr kernel deleted).
    mfma_gemm<<<dim3(3072 / 128, ROWS / 128), 256, 0, stream>>>(
        h, w2t, nullptr, nullptr, nullptr, nullptr, qkv, vt,
        ROWS, 3072, N_EMBD, 0, 0);
    // attn: grid (bh=32, pair=16) -> XCD = bh%8; uniform 33 tiles/block
    attn_k<<<dim3(BATCH * N_HEAD, 16), 256, 0, stream>>>(qkv, vt, att);
    // proj split-K=2, BM=64 tiles (1024 blocks) -> raw partials p0p/p1p
    mfma_gemm64<<<dim3(8, 64, 2), 256, 0, stream>>>(att, wpt, p0p, p1p, N_EMBD, 512);
    // fused proj-epilogue + LN2: x2 = p0p+p1p+bproj+x ; h2 = LN(x2)
    pln_fin<<<ROWS, 256, 0, stream>>>(p0p, p1p, bproj, x, g2, b2, x2, h2);
    // FF1 + bias + relu -> bf16 ff   (256^2 tile, 8-wave, 256 blocks = 1/CU)
    mfma_gemm256<<<dim3(4096 / 256, ROWS / 256), 512, 0, stream>>>(
        h2, wf1t, bff1, ff, 4096, N_EMBD, 1);
    // FF2 split-K=2, BM=64 tiles (1024 blocks) -> p0f / out (raw)
    mfma_gemm64<<<dim3(8, 64, 2), 256, 0, stream>>>(ff, wf2t, p0f, out, 4096, 2048);
    // out = p0f + out + bias + x2
    ff2_fin<<<ROWS * N_EMBD / 1024, 256, 0, stream>>>(p0f, bff2, x2, out);
}

// Round 11
// 348.072 us; speedup vs baseline: 1.0614x; 1.0302x over previous
//
#include <hip/hip_runtime.h>
#include <hip/hip_bf16.h>

#define N_EMBD 1024
#define N_HEAD 16
#define HEADSZ 64
#define BATCH  2
#define SEQ    2048
#define ROWS   (BATCH*SEQ)   /* 4096 */

typedef __attribute__((ext_vector_type(8))) short bf16x8;
typedef __attribute__((ext_vector_type(4))) float f32x4;

__device__ __forceinline__ short f2bs(float v){
    union { __hip_bfloat16 b; short s; } u; u.b = __float2bfloat16(v); return u.s;
}
__device__ __forceinline__ short scale8th(short s){   // exact: *0.125 (pow2)
    union { unsigned i; float f; } u; u.i = ((unsigned)(unsigned short)s) << 16;
    return f2bs(u.f * 0.125f);
}
__device__ __forceinline__ void gload16(const short* g, short* l){
    __builtin_amdgcn_global_load_lds(
        (const __attribute__((address_space(1))) unsigned int*)g,
        (__attribute__((address_space(3))) unsigned int*)l, 16, 0, 0);
}

// ---------------------------------------------------------------------------
// Transpose + f32->bf16 convert: out[j][i] = in[i][j]; in is [R][Cc] f32.
// ---------------------------------------------------------------------------
__global__ __launch_bounds__(256) void tr_cvt(const float* __restrict__ in,
                                              short* __restrict__ out,
                                              int R, int Cc,
                                              size_t in_z, size_t out_z)
{
    __shared__ float t[32][33];
    const int tx = threadIdx.x & 31, ty = threadIdx.x >> 5;
    const int j0 = blockIdx.x * 32, i0 = blockIdx.y * 32;
    const float* ip = in + (size_t)blockIdx.z * in_z;
    short* op = out + (size_t)blockIdx.z * out_z;
#pragma unroll
    for (int p = 0; p < 4; ++p)
        t[ty + p * 8][tx] = ip[(size_t)(i0 + ty + p * 8) * Cc + j0 + tx];
    __syncthreads();
#pragma unroll
    for (int p = 0; p < 4; ++p)
        op[(size_t)(j0 + ty + p * 8) * R + i0 + tx] = f2bs(t[tx][ty + p * 8]);
}

// Fused Wq/Wk/Wv transpose: z = which*16 + head; per-head [1024][64] -> [64][1024]
__global__ __launch_bounds__(256) void tr3_cvt(const float* __restrict__ Wq,
                                               const float* __restrict__ Wk,
                                               const float* __restrict__ Wv,
                                               short* __restrict__ w2t)
{
    __shared__ float t[32][33];
    const int tx = threadIdx.x & 31, ty = threadIdx.x >> 5;
    const int which = blockIdx.z >> 4, head = blockIdx.z & 15;
    const int j0 = blockIdx.x * 32, i0 = blockIdx.y * 32;
    const float* ip = (which == 0 ? Wq : which == 1 ? Wk : Wv) + (size_t)head * 65536;
    short* op = w2t + (size_t)which * 1048576 + (size_t)head * 65536;
#pragma unroll
    for (int p = 0; p < 4; ++p)
        t[ty + p * 8][tx] = ip[(size_t)(i0 + ty + p * 8) * 64 + j0 + tx];
    __syncthreads();
#pragma unroll
    for (int p = 0; p < 4; ++p)
        op[(size_t)(j0 + ty + p * 8) * 1024 + i0 + tx] = f2bs(t[tx][ty + p * 8]);
}

// ---------------------------------------------------------------------------
// LayerNorm (LN1): one block per row of 1024, float4 loads, bf16 output
// ---------------------------------------------------------------------------
__global__ __launch_bounds__(256) void ln_k(const float* __restrict__ x,
                                            const float* __restrict__ g,
                                            const float* __restrict__ bta,
                                            short* __restrict__ out)
{
    const int row = blockIdx.x;
    const int tid = threadIdx.x;
    const float* xr = x + (size_t)row * N_EMBD;
    float4 v = *(const float4*)(xr + tid * 4);
    float s  = v.x + v.y + v.z + v.w;
    float s2 = v.x * v.x + v.y * v.y + v.z * v.z + v.w * v.w;
#pragma unroll
    for (int off = 32; off; off >>= 1) {
        s  += __shfl_xor(s,  off, 64);
        s2 += __shfl_xor(s2, off, 64);
    }
    __shared__ float rs[4], rs2[4];
    const int wave = tid >> 6, lane = tid & 63;
    if (lane == 0) { rs[wave] = s; rs2[wave] = s2; }
    __syncthreads();
    s  = rs[0] + rs[1] + rs[2] + rs[3];
    s2 = rs2[0] + rs2[1] + rs2[2] + rs2[3];
    const float mean = s * (1.f / N_EMBD);
    const float var  = s2 * (1.f / N_EMBD) - mean * mean;
    const float rsig = rsqrtf(var + 1e-5f);
    float4 gv = *(const float4*)(g + tid * 4);
    float4 bv = *(const float4*)(bta + tid * 4);
    short4 o;
    o.x = f2bs((v.x - mean) * rsig * gv.x + bv.x);
    o.y = f2bs((v.y - mean) * rsig * gv.y + bv.y);
    o.z = f2bs((v.z - mean) * rsig * gv.z + bv.z);
    o.w = f2bs((v.w - mean) * rsig * gv.w + bv.w);
    *(short4*)(out + (size_t)row * N_EMBD + tid * 4) = o;
}

// ---------------------------------------------------------------------------
// Fused proj-finalize + LN2: x2 = p0+p1+bias+x (write f32); h2 = LN(x2) bf16.
// ---------------------------------------------------------------------------
__global__ __launch_bounds__(256) void pln_fin(const float* __restrict__ p0,
                                               const float* __restrict__ p1,
                                               const float* __restrict__ bias,
                                               const float* __restrict__ x,
                                               const float* __restrict__ g,
                                               const float* __restrict__ bta,
                                               float* __restrict__ x2,
                                               short* __restrict__ h2)
{
    const int row = blockIdx.x, tid = threadIdx.x;
    const size_t base = (size_t)row * N_EMBD + tid * 4;
    float4 a  = *(const float4*)(p0 + base);
    float4 c  = *(const float4*)(p1 + base);
    float4 xx = *(const float4*)(x + base);
    float4 bb = *(const float4*)(bias + tid * 4);
    float4 v;
    v.x = a.x + c.x + xx.x + bb.x;
    v.y = a.y + c.y + xx.y + bb.y;
    v.z = a.z + c.z + xx.z + bb.z;
    v.w = a.w + c.w + xx.w + bb.w;
    *(float4*)(x2 + base) = v;
    float s  = v.x + v.y + v.z + v.w;
    float s2 = v.x * v.x + v.y * v.y + v.z * v.z + v.w * v.w;
#pragma unroll
    for (int off = 32; off; off >>= 1) {
        s  += __shfl_xor(s,  off, 64);
        s2 += __shfl_xor(s2, off, 64);
    }
    __shared__ float rs[4], rs2[4];
    const int wave = tid >> 6, lane = tid & 63;
    if (lane == 0) { rs[wave] = s; rs2[wave] = s2; }
    __syncthreads();
    s  = rs[0] + rs[1] + rs[2] + rs[3];
    s2 = rs2[0] + rs2[1] + rs2[2] + rs2[3];
    const float mean = s * (1.f / N_EMBD);
    const float var  = s2 * (1.f / N_EMBD) - mean * mean;
    const float rsig = rsqrtf(var + 1e-5f);
    float4 gv = *(const float4*)(g + tid * 4);
    float4 bv = *(const float4*)(bta + tid * 4);
    short4 o;
    o.x = f2bs((v.x - mean) * rsig * gv.x + bv.x);
    o.y = f2bs((v.y - mean) * rsig * gv.y + bv.y);
    o.z = f2bs((v.z - mean) * rsig * gv.z + bv.z);
    o.w = f2bs((v.w - mean) * rsig * gv.w + bv.w);
    *(short4*)(h2 + base) = o;
}

// ---------------------------------------------------------------------------
// MFMA GEMM 128x128, 3-buffer depth-2 counted-vmcnt pipeline (R15).
// Used for QKV. V-region blocks (col0>=2048, block-uniform) write
// TRANSPOSED bf16 directly into vtout[c-2048][token] (vt_tr deleted, R19).
// ---------------------------------------------------------------------------
__global__ __launch_bounds__(256) void mfma_gemm(
    const short* __restrict__ A,    // [M][K] bf16
    const short* __restrict__ Bt,   // [N][K] bf16
    const float* __restrict__ bias,
    const float* __restrict__ resid,
    float* __restrict__ outf,
    float* __restrict__ outf2,
    short* __restrict__ outb,
    short* __restrict__ vtout,      // if set: cols>=2048 -> vt[c-2048][tok]
    int M, int N, int K, int kz, int relu)
{
    __shared__ __align__(16) short As[3][128 * 32];
    __shared__ __align__(16) short Bs[3][128 * 32];
    const int tid  = threadIdx.x;
    const int lane = tid & 63, w = tid >> 6;
    const int quad = lane >> 4, l16 = lane & 15;
    const int row0 = blockIdx.y * 128, col0 = blockIdx.x * 128;
    const int wm = (w >> 1) * 64, wn = (w & 1) * 64;
    const int koff = blockIdx.z * kz;
    const int kend = kz ? kz : K;
    const int nk   = kend >> 5;          // 32-wide K tiles

    f32x4 acc[4][4];
#pragma unroll
    for (int i = 0; i < 4; ++i)
#pragma unroll
        for (int j = 0; j < 4; ++j)
            acc[i][j] = f32x4{0.f, 0.f, 0.f, 0.f};

    const int c0  = w * 128 + lane;
    const int c1  = c0 + 64;
    const int ar0 = c0 >> 2, ak0 = (((c0 & 3) ^ ((ar0 >> 1) & 3))) * 8; // swizzled
    const int ar1 = c1 >> 2, ak1 = (((c1 & 3) ^ ((ar1 >> 1) & 3))) * 8;
    const short* aG0 = A  + (size_t)(row0 + ar0) * K + koff + ak0;
    const short* aG1 = A  + (size_t)(row0 + ar1) * K + koff + ak1;
    const short* bG0 = Bt + (size_t)(col0 + ar0) * K + koff + ak0;
    const short* bG1 = Bt + (size_t)(col0 + ar1) * K + koff + ak1;
    const int lofs = w * 1024;

    const int gsw = (quad ^ ((l16 >> 1) & 3)) * 8;   // swizzled frag chunk

    // prologue: stage T0 -> buf0, T1 -> buf1 (4 loads/wave each)
    gload16(aG0, As[0] + lofs);
    gload16(aG1, As[0] + lofs + 512);
    gload16(bG0, Bs[0] + lofs);
    gload16(bG1, Bs[0] + lofs + 512);
    if (nk > 1) {
        gload16(aG0 + 32, As[1] + lofs);
        gload16(aG1 + 32, As[1] + lofs + 512);
        gload16(bG0 + 32, Bs[1] + lofs);
        gload16(bG1 + 32, Bs[1] + lofs + 512);
    }

    for (int k = 0; k < nk; ++k) {
        if (k + 1 < nk) asm volatile("s_waitcnt vmcnt(4)" ::: "memory");
        else            asm volatile("s_waitcnt vmcnt(0)" ::: "memory");
        __builtin_amdgcn_s_barrier();
        if (k + 2 < nk) {
            const int nb = (k + 2) % 3;
            const int ko = (k + 2) * 32;
            gload16(aG0 + ko, As[nb] + lofs);
            gload16(aG1 + ko, As[nb] + lofs + 512);
            gload16(bG0 + ko, Bs[nb] + lofs);
            gload16(bG1 + ko, Bs[nb] + lofs + 512);
        }
        const int cur = k % 3;

        bf16x8 af[4], bfr[4];
#pragma unroll
        for (int i = 0; i < 4; ++i)
            af[i]  = *(const bf16x8*)(As[cur] + (wm + i * 16 + l16) * 32 + gsw);
#pragma unroll
        for (int j = 0; j < 4; ++j)
            bfr[j] = *(const bf16x8*)(Bs[cur] + (wn + j * 16 + l16) * 32 + gsw);
#pragma unroll
        for (int i = 0; i < 4; ++i)
#pragma unroll
            for (int j = 0; j < 4; ++j)
                acc[i][j] = __builtin_amdgcn_mfma_f32_16x16x32_bf16(
                    af[i], bfr[j], acc[i][j], 0, 0, 0);
    }

    if (vtout && col0 >= 2048) {     // V region: write transposed bf16
#pragma unroll
        for (int i = 0; i < 4; ++i) {
            const int rbase = row0 + wm + i * 16 + quad * 4;   // token base (x4)
#pragma unroll
            for (int j = 0; j < 4; ++j) {
                const int c = col0 + wn + j * 16 + l16 - 2048; // V channel
                short4 pv;
                pv.x = f2bs(acc[i][j][0]); pv.y = f2bs(acc[i][j][1]);
                pv.z = f2bs(acc[i][j][2]); pv.w = f2bs(acc[i][j][3]);
                *(short4*)(vtout + (size_t)c * 4096 + rbase) = pv;
            }
        }
        return;
    }

    float* of = blockIdx.z ? outf2 : outf;
#pragma unroll
    for (int i = 0; i < 4; ++i) {
        const int rbase = row0 + wm + i * 16 + quad * 4;
#pragma unroll
        for (int j = 0; j < 4; ++j) {
            const int c = col0 + wn + j * 16 + l16;
            const float bv = bias ? bias[c] : 0.f;
#pragma unroll
            for (int r = 0; r < 4; ++r) {
                float v = acc[i][j][r] + bv;
                if (relu) v = fmaxf(v, 0.f);
                const size_t idx = (size_t)(rbase + r) * N + c;
                if (resid) v += resid[idx];
                if (outb) outb[idx] = f2bs(v);
                else      of[idx] = v;
            }
        }
    }
}

// ---------------------------------------------------------------------------
// MFMA GEMM 256x256, 8 waves (2M x 4N), per-wave 128x64 output.
// R20: BK=64 (was 32). R19 counters: FF1 at 553 TF = the 2-phase
// per-iteration-overhead floor (m233: stage+drain+2 barriers ~72%/iter).
// BK=64 halves the iteration count (16 vs 32) at identical work/FLOP.
// LDS 2 x 64KB = 128KB (1 block/CU, grid-forced anyway). Staging: 2048
// 16B-chunks/matrix/K-tile, 4 gload16/thread/matrix; slot p holds row
// p>>3, k-chunk (p&7)^(row&7) (both-sides XOR, rows = 128B = bank period).
// Frag read inverts: slot = (ks*4+quad)^(l16&7). Issue-early depth-1.
// ---------------------------------------------------------------------------
__global__ __launch_bounds__(512, 2) void mfma_gemm256(
    const short* __restrict__ A,    // [M][K] bf16
    const short* __restrict__ Bt,   // [N][K] bf16
    const float* __restrict__ bias,
    short* __restrict__ outb,       // [M][N] bf16
    int N, int K, int relu)
{
    __shared__ __align__(16) short As[2][256 * 64];
    __shared__ __align__(16) short Bs[2][256 * 64];
    const int tid  = threadIdx.x;              // 0..511
    const int lane = tid & 63, w = tid >> 6;   // 8 waves
    const int quad = lane >> 4, l16 = lane & 15;
    const int row0 = blockIdx.y * 256, col0 = blockIdx.x * 256;
    const int wm = (w >> 2) * 128;             // 2 row-halves
    const int wn = (w & 3) * 64;               // 4 col-quarters
    const int nk = K >> 6;                     // BK=64 K-tiles

    f32x4 acc[8][4];
#pragma unroll
    for (int i = 0; i < 8; ++i)
#pragma unroll
        for (int j = 0; j < 4; ++j)
            acc[i][j] = f32x4{0.f, 0.f, 0.f, 0.f};

    // staging slot p_j = j*512 + tid; row r = p>>3, k-chunk c = (p&7)^(r&7)
    const short* aG[4];
    const short* bG[4];
    int lofs[4];
#pragma unroll
    for (int j = 0; j < 4; ++j) {
        const int p = j * 512 + tid;
        const int r = p >> 3;
        const int c = (p & 7) ^ (r & 7);
        aG[j] = A  + (size_t)(row0 + r) * K + c * 8;
        bG[j] = Bt + (size_t)(col0 + r) * K + c * 8;
        lofs[j] = j * 4096 + w * 512;          // shorts; lane*16B added by HW
    }
    const int e = l16 & 7;

    // prologue: stage T0 -> buf 0
#pragma unroll
    for (int j = 0; j < 4; ++j) {
        gload16(aG[j], As[0] + lofs[j]);
        gload16(bG[j], Bs[0] + lofs[j]);
    }
    asm volatile("s_waitcnt vmcnt(0)" ::: "memory");
    __builtin_amdgcn_s_barrier();

    for (int k = 0; k < nk; ++k) {
        const int cur = k & 1;
        if (k + 1 < nk) {                      // stage next K-tile -> other buf
            const int ko = (k + 1) * 64;
            const int nb = cur ^ 1;
#pragma unroll
            for (int j = 0; j < 4; ++j) {
                gload16(aG[j] + ko, As[nb] + lofs[j]);
                gload16(bG[j] + ko, Bs[nb] + lofs[j]);
            }
        }

#pragma unroll
        for (int ks = 0; ks < 2; ++ks) {       // two K=32 halves of the tile
            const int sA = ((ks * 4 + quad) ^ e) * 8;
            bf16x8 af[8], bfr[4];
#pragma unroll
            for (int i = 0; i < 8; ++i)
                af[i] = *(const bf16x8*)(As[cur] + (wm + i * 16 + l16) * 64 + sA);
#pragma unroll
            for (int j = 0; j < 4; ++j)
                bfr[j] = *(const bf16x8*)(Bs[cur] + (wn + j * 16 + l16) * 64 + sA);
#pragma unroll
            for (int i = 0; i < 8; ++i)
#pragma unroll
                for (int j = 0; j < 4; ++j)
                    acc[i][j] = __builtin_amdgcn_mfma_f32_16x16x32_bf16(
                        af[i], bfr[j], acc[i][j], 0, 0, 0);
        }

        // next tile landed + all waves done reading buf[cur]
        asm volatile("s_waitcnt vmcnt(0)" ::: "memory");
        __builtin_amdgcn_s_barrier();
    }

#pragma unroll
    for (int i = 0; i < 8; ++i) {
        const int rbase = row0 + wm + i * 16 + quad * 4;
#pragma unroll
        for (int j = 0; j < 4; ++j) {
            const int c = col0 + wn + j * 16 + l16;
            const float bv = bias[c];
#pragma unroll
            for (int r = 0; r < 4; ++r) {
                float v = acc[i][j][r] + bv;
                if (relu) v = fmaxf(v, 0.f);
                outb[(size_t)(rbase + r) * N + c] = f2bs(v);
            }
        }
    }
}

// ---------------------------------------------------------------------------
// MFMA GEMM 64x128, 3-buffer depth-2 counted-vmcnt pipeline (3 loads/tile
// per wave -> vmcnt(3)). XCD-chunked bijective block swizzle. 36 KB LDS
// (4 blocks/CU). Raw f32 partials (z -> outf/outf2). For proj and FF2.
// ---------------------------------------------------------------------------
__global__ __launch_bounds__(256) void mfma_gemm64(
    const short* __restrict__ A,    // [4096][K] bf16
    const short* __restrict__ Bt,   // [1024][K] bf16
    float* __restrict__ outf,
    float* __restrict__ outf2,
    int K, int kz)
{
    __shared__ __align__(16) short As[3][64 * 32];
    __shared__ __align__(16) short Bs[3][128 * 32];
    const int tid  = threadIdx.x;
    const int lane = tid & 63, w = tid >> 6;
    const int quad = lane >> 4, l16 = lane & 15;
    const int lin  = (int)blockIdx.y * 8 + (int)blockIdx.x;   // 0..511
    const int swz  = (lin & 7) * 64 + (lin >> 3);
    const int col0 = (swz & 7) * 128;
    const int row0 = (swz >> 3) * 64;
    const int wr = w >> 1, wc = w & 1;                        // 2x2 wave tiles
    const int koff = blockIdx.z * kz;
    const int nk   = kz >> 5;

    f32x4 acc[2][4];
#pragma unroll
    for (int i = 0; i < 2; ++i)
#pragma unroll
        for (int j = 0; j < 4; ++j)
            acc[i][j] = f32x4{0.f, 0.f, 0.f, 0.f};

    // A staging: 1 gload16/thread (64 rows x 32 K)
    const int ia  = w * 64 + lane;                 // 0..255
    const int ar  = ia >> 2;                       // 0..63
    const int aak = ((ia & 3) ^ ((ar >> 1) & 3)) * 8;
    const short* aG = A + (size_t)(row0 + ar) * K + koff + aak;
    const int aofs = w * 512;
    // B staging: 2 gload16/thread (128 rows x 32 K)
    const int c0  = w * 128 + lane;
    const int c1  = c0 + 64;
    const int br0 = c0 >> 2, bk0 = ((c0 & 3) ^ ((br0 >> 1) & 3)) * 8;
    const int br1 = c1 >> 2, bk1 = ((c1 & 3) ^ ((br1 >> 1) & 3)) * 8;
    const short* bG0 = Bt + (size_t)(col0 + br0) * K + koff + bk0;
    const short* bG1 = Bt + (size_t)(col0 + br1) * K + koff + bk1;
    const int bofs = w * 1024;

    const int gsw = (quad ^ ((l16 >> 1) & 3)) * 8;

    // prologue: stage T0 -> buf0, T1 -> buf1
    gload16(aG, As[0] + aofs);
    gload16(bG0, Bs[0] + bofs);
    gload16(bG1, Bs[0] + bofs + 512);
    if (nk > 1) {
        gload16(aG + 32, As[1] + aofs);
        gload16(bG0 + 32, Bs[1] + bofs);
        gload16(bG1 + 32, Bs[1] + bofs + 512);
    }

    for (int k = 0; k < nk; ++k) {
        if (k + 1 < nk) asm volatile("s_waitcnt vmcnt(3)" ::: "memory");
        else            asm volatile("s_waitcnt vmcnt(0)" ::: "memory");
        __builtin_amdgcn_s_barrier();
        if (k + 2 < nk) {
            const int nb = (k + 2) % 3;
            const int ko = (k + 2) * 32;
            gload16(aG + ko, As[nb] + aofs);
            gload16(bG0 + ko, Bs[nb] + bofs);
            gload16(bG1 + ko, Bs[nb] + bofs + 512);
        }
        const int cur = k % 3;

        bf16x8 af[2], bfr[4];
#pragma unroll
        for (int i = 0; i < 2; ++i)
            af[i]  = *(const bf16x8*)(As[cur] + (wr * 32 + i * 16 + l16) * 32 + gsw);
#pragma unroll
        for (int j = 0; j < 4; ++j)
            bfr[j] = *(const bf16x8*)(Bs[cur] + (wc * 64 + j * 16 + l16) * 32 + gsw);
#pragma unroll
        for (int i = 0; i < 2; ++i)
#pragma unroll
            for (int j = 0; j < 4; ++j)
                acc[i][j] = __builtin_amdgcn_mfma_f32_16x16x32_bf16(
                    af[i], bfr[j], acc[i][j], 0, 0, 0);
    }

    float* of = blockIdx.z ? outf2 : outf;
#pragma unroll
    for (int i = 0; i < 2; ++i) {
        const int rbase = row0 + wr * 32 + i * 16 + quad * 4;
#pragma unroll
        for (int j = 0; j < 4; ++j) {
            const int c = col0 + wc * 64 + j * 16 + l16;
#pragma unroll
            for (int r = 0; r < 4; ++r)
                of[(size_t)(rbase + r) * 1024 + c] = acc[i][j][r];
        }
    }
}

// ---------------------------------------------------------------------------
// FF2 finalize: out = p0 + out + bias + x2   (all f32, N=1024 bias period)
// ---------------------------------------------------------------------------
__global__ __launch_bounds__(256) void ff2_fin(const float* __restrict__ p0,
                                               const float* __restrict__ bias,
                                               const float* __restrict__ x2,
                                               float* __restrict__ out)
{
    const size_t i = ((size_t)blockIdx.x * 256 + threadIdx.x) * 4;
    float4 a = *(const float4*)(p0 + i);
    float4 b = *(const float4*)(out + i);
    float4 r = *(const float4*)(x2 + i);
    float4 bb = *(const float4*)(bias + (i & 1023));
    float4 o;
    o.x = a.x + b.x + r.x + bb.x;
    o.y = a.y + b.y + r.y + bb.y;
    o.z = a.z + b.z + r.z + bb.z;
    o.w = a.w + b.w + r.w + bb.w;
    *(float4*)(out + i) = o;
}

// ---------------------------------------------------------------------------
// MFMA flash attention (R17 structure + R19 defer-max):
// grid = (bh=32, pair=16): XCD = bh%8 (K/V L2-resident); each block does
// qt = pair and qt = 31-pair -> uniform 33 tiles. Swapped QK^T softmax.
// T13 defer-max (THR=8): skip O-rescale + max-update when growth <= 8.
// ---------------------------------------------------------------------------
__global__ __launch_bounds__(256) void attn_k(const short* __restrict__ qkv,
                                              const short* __restrict__ vt,
                                              short* __restrict__ att)
{
    __shared__ __align__(16) short Ks[2][64 * 64];   // [s][d] swizzled
    __shared__ __align__(16) short Vs[2][64 * 64];   // [d][s] swizzled
    __shared__ __align__(16) short Ps[64 * 64];      // [q][s] XOR-swizzled
    const int tid  = threadIdx.x;
    const int lane = tid & 63, w = tid >> 6;         // w in 0..3
    const int quad = lane >> 4, l16 = lane & 15;
    const int bh = blockIdx.x, b = bh >> 4, head = bh & 15;  // XCD=bh%8

    const int srow = lane >> 3;                       // 0..7
    const int sw   = ((lane & 7) ^ srow) * 8;         // staging swizzle (shorts)
    const int cidx = (quad ^ (l16 & 7)) * 8;          // frag-read swizzle

#pragma unroll
    for (int pass = 0; pass < 2; ++pass) {
        const int qt = pass == 0 ? (int)blockIdx.y : 31 - (int)blockIdx.y;
        const int t0 = qt * 64;
        const int ntiles = qt + 1;

        // Q fragments (registers), scale folded in (exact pow2)
        const short* qp = qkv + (size_t)(b * SEQ + t0 + w * 16 + l16) * 3072
                          + head * 64 + quad * 8;
        bf16x8 qf0 = *(const bf16x8*)qp;
        bf16x8 qf1 = *(const bf16x8*)(qp + 32);
#pragma unroll
        for (int i = 0; i < 8; ++i) { qf0[i] = scale8th(qf0[i]); qf1[i] = scale8th(qf1[i]); }

        // per-lane softmax state for q-row (t0 + w*16 + l16)
        float mrow = -INFINITY, lrow = 0.f;
        f32x4 O[4];                                   // D[q=w*16+quad*4+r][d=jn*16+l16]
#pragma unroll
        for (int jn = 0; jn < 4; ++jn) O[jn] = f32x4{0.f, 0.f, 0.f, 0.f};

        // guard: previous pass fully done before overwriting buf0
        asm volatile("s_waitcnt vmcnt(0) lgkmcnt(0)\n\ts_barrier" ::: "memory");
        {   // prefetch tile 0 -> buffer 0 (wave w: K rows / V d-rows [w*16,+16))
            const short* kg = qkv + (size_t)(b * SEQ + w * 16 + srow) * 3072
                              + 1024 + head * 64 + sw;
            const short* vg = vt + (size_t)(head * 64 + w * 16 + srow) * 4096
                              + b * SEQ + sw;
            short* kL = Ks[0] + w * 1024;
            short* vL = Vs[0] + w * 1024;
            gload16(kg, kL); gload16(kg + (size_t)8 * 3072, kL + 512);
            gload16(vg, vL); gload16(vg + (size_t)8 * 4096, vL + 512);
        }

        for (int kt = 0; kt < ntiles; ++kt) {
            const int cur = kt & 1;
            // prefetched tile kt landed (all waves), prev compute done
            asm volatile("s_waitcnt vmcnt(0) lgkmcnt(0)\n\ts_barrier" ::: "memory");
            if (kt + 1 < ntiles) {
                const int s1 = (kt + 1) * 64;
                const short* kg = qkv + (size_t)(b * SEQ + s1 + w * 16 + srow) * 3072
                                  + 1024 + head * 64 + sw;
                const short* vg = vt + (size_t)(head * 64 + w * 16 + srow) * 4096
                                  + b * SEQ + s1 + sw;
                short* kL = Ks[cur ^ 1] + w * 1024;
                short* vL = Vs[cur ^ 1] + w * 1024;
                gload16(kg, kL); gload16(kg + (size_t)8 * 3072, kL + 512);
                gload16(vg, vL); gload16(vg + (size_t)8 * 4096, vL + 512);
            }

            // --- S^T = K.Q^T : D[key=jn*16+quad*4+r][q=l16] (swapped) ---
            f32x4 S[4];
            const short* Kb = Ks[cur];
#pragma unroll
            for (int jn = 0; jn < 4; ++jn) {
                S[jn] = f32x4{0.f, 0.f, 0.f, 0.f};
                const short* kp = Kb + (jn * 16 + l16) * 64;
                bf16x8 b0 = *(const bf16x8*)(kp + cidx);
                bf16x8 b1 = *(const bf16x8*)(kp + (cidx ^ 32));
                S[jn] = __builtin_amdgcn_mfma_f32_16x16x32_bf16(b0, qf0, S[jn], 0, 0, 0);
                S[jn] = __builtin_amdgcn_mfma_f32_16x16x32_bf16(b1, qf1, S[jn], 0, 0, 0);
            }

            // --- softmax: q = t0 + w*16 + l16 fixed per lane ---
            float Sv[4][4];
            const int qrow = t0 + w * 16 + l16;
            const int s0 = kt * 64;
#pragma unroll
            for (int jn = 0; jn < 4; ++jn)
#pragma unroll
                for (int r = 0; r < 4; ++r)
                    Sv[jn][r] = S[jn][r];
            if (kt == ntiles - 1) {   // diagonal tile
#pragma unroll
                for (int jn = 0; jn < 4; ++jn)
#pragma unroll
                    for (int r = 0; r < 4; ++r)
                        if (s0 + jn * 16 + quad * 4 + r > qrow) Sv[jn][r] = -INFINITY;
            }
            float tmx[4];
#pragma unroll
            for (int jn = 0; jn < 4; ++jn)
                tmx[jn] = fmaxf(fmaxf(Sv[jn][0], Sv[jn][1]), fmaxf(Sv[jn][2], Sv[jn][3]));
            float pm = fmaxf(fmaxf(tmx[0], tmx[1]), fmaxf(tmx[2], tmx[3]));
            pm = fmaxf(pm, __shfl_xor(pm, 16, 64));
            pm = fmaxf(pm, __shfl_xor(pm, 32, 64));  // full 64-key max

            // defer-max (T13): skip rescale when max growth <= 8 for ALL rows
            const bool skip = __all(pm - mrow <= 8.f);   // first tile: false
            const float mn = skip ? mrow : fmaxf(mrow, pm);
#pragma unroll
            for (int jn = 0; jn < 4; ++jn)
#pragma unroll
                for (int r = 0; r < 4; ++r)
                    Sv[jn][r] = __expf(Sv[jn][r] - mn);
            float tsm[4];
#pragma unroll
            for (int jn = 0; jn < 4; ++jn)
                tsm[jn] = (Sv[jn][0] + Sv[jn][1]) + (Sv[jn][2] + Sv[jn][3]);
            float ps = (tsm[0] + tsm[1]) + (tsm[2] + tsm[3]);
            ps += __shfl_xor(ps, 16, 64);
            ps += __shfl_xor(ps, 32, 64);
            if (skip) {
                lrow += ps;
            } else {
                const float alpha = __expf(mrow - mn);   // 0 on first tile
                lrow = lrow * alpha + ps;
                mrow = mn;
                // rescale O: alpha for O-row (quad*4+r) at lane l16==quad*4+r
#pragma unroll
                for (int r = 0; r < 4; ++r) {
                    const float a = __shfl(alpha, quad * 4 + r, 64);
#pragma unroll
                    for (int jn = 0; jn < 4; ++jn) O[jn][r] *= a;
                }
            }

            // --- P^T -> LDS rows [q][key] ---
#pragma unroll
            for (int jn = 0; jn < 4; ++jn) {
                short4 pv;
                pv.x = f2bs(Sv[jn][0]); pv.y = f2bs(Sv[jn][1]);
                pv.z = f2bs(Sv[jn][2]); pv.w = f2bs(Sv[jn][3]);
                const int prow = w * 16 + l16;
                const int pcol = jn * 16 + quad * 4;  // 4-aligned
                const int chunk = (pcol >> 3) ^ (l16 & 7);
                *(short4*)(Ps + prow * 64 + chunk * 8 + (pcol & 7)) = pv;
            }
            asm volatile("s_waitcnt lgkmcnt(0)" ::: "memory");

            // --- O += P.V ---
            const short* pp = Ps + (w * 16 + l16) * 64;
            bf16x8 pf0 = *(const bf16x8*)(pp + cidx);
            bf16x8 pf1 = *(const bf16x8*)(pp + (cidx ^ 32));
            const short* Vb = Vs[cur];
#pragma unroll
            for (int jn = 0; jn < 4; ++jn) {
                const short* vp = Vb + (jn * 16 + l16) * 64;
                bf16x8 v0 = *(const bf16x8*)(vp + cidx);
                bf16x8 v1 = *(const bf16x8*)(vp + (cidx ^ 32));
                O[jn] = __builtin_amdgcn_mfma_f32_16x16x32_bf16(pf0, v0, O[jn], 0, 0, 0);
                O[jn] = __builtin_amdgcn_mfma_f32_16x16x32_bf16(pf1, v1, O[jn], 0, 0, 0);
            }
        }

        // --- write O (rows quad*4+r need 1/l from lane l16==quad*4+r) ---
#pragma unroll
        for (int r = 0; r < 4; ++r) {
            const float lr  = __shfl(lrow, quad * 4 + r, 64);
            const float inv = 1.f / lr;
            const size_t rowoff = (size_t)(b * SEQ + t0 + w * 16 + quad * 4 + r) * N_EMBD
                                  + head * 64 + l16;
#pragma unroll
            for (int jn = 0; jn < 4; ++jn)
                att[rowoff + jn * 16] = f2bs(O[jn][r] * inv);
        }
    }
}

// ---------------------------------------------------------------------------
extern "C" void kernel_launch(void* const* d_in, const int* in_sizes, int n_in,
                              void* d_out, int out_size, void* d_ws, size_t ws_size,
                              hipStream_t stream)
{
    const float* x     = (const float*)d_in[0];
    const float* Wq    = (const float*)d_in[1];
    const float* Wk    = (const float*)d_in[2];
    const float* Wv    = (const float*)d_in[3];
    const float* Wproj = (const float*)d_in[4];
    const float* bproj = (const float*)d_in[5];
    const float* g1    = (const float*)d_in[6];
    const float* b1    = (const float*)d_in[7];
    const float* g2    = (const float*)d_in[8];
    const float* b2    = (const float*)d_in[9];
    const float* Wff1  = (const float*)d_in[10];
    const float* bff1  = (const float*)d_in[11];
    const float* Wff2  = (const float*)d_in[12];
    const float* bff2  = (const float*)d_in[13];
    float* out = (float*)d_out;

    char* ws = (char*)d_ws;
    short* w2t  = (short*)(ws + 0);          // [3072][1024] bf16 (dead after QKV)
    short* wpt  = (short*)(ws + 6291456);    // [1024][1024] (dead after proj)
    short* wf1t = (short*)(ws + 8388608);    // [4096][1024] (dead after FF1)
    short* wf2t = (short*)(ws + 16777216);   // [1024][4096]
    short* h    = (short*)(ws + 25165824);   // [4096][1024] (=h2)
    short* qkv  = (short*)(ws + 33554432);   // [4096][3072] (dead after attn)
    short* vt   = (short*)(ws + 58720256);   // [1024][4096] (dead after attn)
    short* att  = (short*)(ws + 67108864);   // [4096][1024]
    float* x2   = (float*)(ws + 75497472);   // [4096][1024] f32
    short* h2   = h;
    float* p0p  = (float*)(ws + 33554432);   // proj partials over dead qkv/vt
    float* p1p  = (float*)(ws + 50331648);
    short* ff   = qkv;                       // [4096][4096] (p0p/p1p dead by FF1)
    float* p0f  = (float*)(ws + 0);          // FF2 partial over w2t+wpt+wf1t (dead)

    tr3_cvt<<<dim3(2, 32, 48),  256, 0, stream>>>(Wq, Wk, Wv, w2t);
    tr_cvt<<<dim3(32, 32, 1),  256, 0, stream>>>(Wproj, wpt,  1024, 1024, 0, 0);
    tr_cvt<<<dim3(128, 32, 1), 256, 0, stream>>>(Wff1, wf1t,  1024, 4096, 0, 0);
    tr_cvt<<<dim3(32, 128, 1), 256, 0, stream>>>(Wff2, wf2t,  4096, 1024, 0, 0);

    ln_k<<<ROWS, 256, 0, stream>>>(x, g1, b1, h);
    // QKV: [4096,1024] x [1024,3072] -> bf16 qkv; V cols written transposed
    // into vt directly (vt_tr kernel deleted).
    mfma_gemm<<<dim3(3072 / 128, ROWS / 128), 256, 0, stream>>>(
        h, w2t, nullptr, nullptr, nullptr, nullptr, qkv, vt,
        ROWS, 3072, N_EMBD, 0, 0);
    // attn: grid (bh=32, pair=16) -> XCD = bh%8; uniform 33 tiles/block
    attn_k<<<dim3(BATCH * N_HEAD, 16), 256, 0, stream>>>(qkv, vt, att);
    // proj split-K=2, BM=64 tiles (1024 blocks) -> raw partials p0p/p1p
    mfma_gemm64<<<dim3(8, 64, 2), 256, 0, stream>>>(att, wpt, p0p, p1p, N_EMBD, 512);
    // fused proj-epilogue + LN2: x2 = p0p+p1p+bproj+x ; h2 = LN(x2)
    pln_fin<<<ROWS, 256, 0, stream>>>(p0p, p1p, bproj, x, g2, b2, x2, h2);
    // FF1 + bias + relu -> bf16 ff   (256^2 tile, BK=64, 256 blocks = 1/CU)
    mfma_gemm256<<<dim3(4096 / 256, ROWS / 256), 512, 0, stream>>>(
        h2, wf1t, bff1, ff, 4096, N_EMBD, 1);
    // FF2 split-K=2, BM=64 tiles (1024 blocks) -> p0f / out (raw)
    mfma_gemm64<<<dim3(8, 64, 2), 256, 0, stream>>>(ff, wf2t, p0f, out, 4096, 2048);
    // out = p0f + out + bias + x2
    ff2_fin<<<ROWS * N_EMBD / 1024, 256, 0, stream>>>(p0f, bff2, x2, out);
}